// Round 1
// baseline (283.036 us; speedup 1.0000x reference)
//
#include <hip/hip_runtime.h>

typedef __attribute__((ext_vector_type(8))) short bf16x8;
typedef __attribute__((ext_vector_type(4))) float f32x4;

typedef const __attribute__((address_space(1))) unsigned int gu32;
typedef __attribute__((address_space(3))) unsigned int lu32;

__device__ __forceinline__ void async16(const void* g, void* l) {
  __builtin_amdgcn_global_load_lds((gu32*)g, (lu32*)l, 16, 0, 0);
}

__device__ __forceinline__ unsigned short f2bf(float f) {
  unsigned int u = __float_as_uint(f);
  u += 0x7fffu + ((u >> 16) & 1u);
  return (unsigned short)(u >> 16);
}
__device__ __forceinline__ float b2f(unsigned short s) {
  return __uint_as_float(((unsigned int)s) << 16);
}

// ---------------- fp32 -> bf16 conversion ----------------
__global__ __launch_bounds__(256) void cvt_k(const float* __restrict__ in,
                                             unsigned short* __restrict__ out,
                                             int n4) {
  int i = blockIdx.x * 256 + threadIdx.x;
  if (i >= n4) return;
  float4 v = ((const float4*)in)[i];
  ushort4 o;
  o.x = f2bf(v.x); o.y = f2bf(v.y); o.z = f2bf(v.z); o.w = f2bf(v.w);
  ((ushort4*)out)[i] = o;
}

// ---------------- GEMM: C[m][n] = sum_k A[m][k] * B[n][k] ----------------
// A: M x K bf16 row-major, B: N x K bf16 row-major (i.e. C = A @ B^T)
// 128x128 tile, BK=64, 4 waves (2x2), each wave 64x64 via 4x4 16x16x32 frags.
template <int WRITE_F32>
__global__ __launch_bounds__(256) void gemm_bt(const unsigned short* __restrict__ A,
                                               const unsigned short* __restrict__ B,
                                               void* __restrict__ Cp, int N, int K) {
  __shared__ __align__(16) unsigned short Al[128 * 64];
  __shared__ __align__(16) unsigned short Bl[128 * 64];
  const int t = threadIdx.x;
  const int w = t >> 6, l = t & 63;
  const int wm = w >> 1, wn = w & 1;
  const int lr = l & 15, lg = l >> 4;
  const long bm = (long)blockIdx.x * 128, bn = (long)blockIdx.y * 128;
  const int srow = t >> 3, scol = (t & 7) * 8;
  f32x4 acc[4][4] = {};
  for (int k0 = 0; k0 < K; k0 += 64) {
    __syncthreads();  // protect LDS while previous iteration may still read
    #pragma unroll
    for (int r = 0; r < 4; ++r) {
      int row = r * 32 + srow;
      async16(&A[(bm + row) * (long)K + k0 + scol], &Al[row * 64 + scol]);
      async16(&B[(bn + row) * (long)K + k0 + scol], &Bl[row * 64 + scol]);
    }
    __syncthreads();  // compiler drains vmcnt before s_barrier
    #pragma unroll
    for (int ks = 0; ks < 2; ++ks) {
      bf16x8 af[4], bf[4];
      #pragma unroll
      for (int i = 0; i < 4; ++i) {
        af[i] = *(const bf16x8*)&Al[(wm * 64 + i * 16 + lr) * 64 + ks * 32 + lg * 8];
        bf[i] = *(const bf16x8*)&Bl[(wn * 64 + i * 16 + lr) * 64 + ks * 32 + lg * 8];
      }
      #pragma unroll
      for (int i = 0; i < 4; ++i)
        #pragma unroll
        for (int j = 0; j < 4; ++j)
          acc[i][j] = __builtin_amdgcn_mfma_f32_16x16x32_bf16(af[i], bf[j], acc[i][j], 0, 0, 0);
    }
  }
  #pragma unroll
  for (int i = 0; i < 4; ++i)
    #pragma unroll
    for (int j = 0; j < 4; ++j)
      #pragma unroll
      for (int r = 0; r < 4; ++r) {
        long row = bm + wm * 64 + i * 16 + lg * 4 + r;  // C: row=(lane>>4)*4+reg
        long col = bn + wn * 64 + j * 16 + lr;          //    col=lane&15
        float v = acc[i][j][r];
        if (WRITE_F32) ((float*)Cp)[row * N + col] = v;
        else ((unsigned short*)Cp)[row * N + col] = f2bf(v);
      }
}

// ---------------- RoPE in-place on Q and K blocks of QKV ----------------
// QKV: 4096 x 3072 bf16; cols [0,1024)=Q, [1024,2048)=K, [2048,3072)=V.
__global__ __launch_bounds__(256) void rope_k(unsigned short* __restrict__ QKV) {
  int idx = blockIdx.x * 256 + threadIdx.x;  // 4096*512 threads
  int row = idx >> 9;
  int rem = idx & 511;
  int h = rem >> 5;
  int i = rem & 31;
  int s = row & 2047;  // position within sequence
  float invf = exp2f((float)i * (-13.287712379549449f / 32.0f));  // 10000^(-i/32)
  float ang = (float)s * invf;
  float sn, cs;
  sincosf(ang, &sn, &cs);
  size_t base = (size_t)row * 3072 + h * 64 + 2 * i;
  #pragma unroll
  for (int qk = 0; qk < 2; ++qk) {
    size_t off = base + (size_t)qk * 1024;
    float x1 = b2f(QKV[off]);
    float x2 = b2f(QKV[off + 1]);
    QKV[off]     = f2bf(x1 * cs - x2 * sn);
    QKV[off + 1] = f2bf(x1 * sn + x2 * cs);
  }
}

// ---------------- causal flash attention ----------------
// grid: x = q-tile (32), y = b*16+h (32). 256 threads, 4 waves; wave w owns
// q rows [qtile*64 + w*16, +16). KV tiles of 64.
__global__ __launch_bounds__(256) void attn_k(const unsigned short* __restrict__ QKV,
                                              unsigned short* __restrict__ O) {
  __shared__ __align__(16) unsigned short Kl[64 * 64];      // K tile, row-major [k][d]
  __shared__ __align__(16) unsigned short Vt[64 * 72];      // V tile transposed [d][k], padded
  __shared__ __align__(16) unsigned short Pl[4][16 * 72];   // per-wave P bounce, padded
  const int t = threadIdx.x;
  const int w = t >> 6, l = t & 63;
  const int lr = l & 15, lg = l >> 4;
  const int qtile = blockIdx.x;
  const int bh = blockIdx.y;
  const int b = bh >> 4, h = bh & 15;
  const int qbase = qtile * 64;
  const long rowb = (long)b * 2048;
  const int L = 3072;
  const int srow = t >> 3, scol = (t & 7) * 8;

  bf16x8 qf[2];
  {
    long qrow = rowb + qbase + w * 16 + lr;
    #pragma unroll
    for (int ks = 0; ks < 2; ++ks)
      qf[ks] = *(const bf16x8*)&QKV[qrow * L + h * 64 + ks * 32 + lg * 8];
  }
  float m[4], lsum[4];
  f32x4 oacc[4] = {};
  #pragma unroll
  for (int r = 0; r < 4; ++r) { m[r] = -1e30f; lsum[r] = 0.0f; }
  const float cexp = 0.125f * 1.4426950408889634f;  // (1/sqrt(64)) * log2(e)

  for (int kt = 0; kt <= qtile; ++kt) {
    const long kbase = (long)kt * 64;
    __syncthreads();  // previous iteration done reading Kl/Vt
    #pragma unroll
    for (int r = 0; r < 2; ++r) {
      int row = r * 32 + srow;
      async16(&QKV[(rowb + kbase + row) * L + 1024 + h * 64 + scol],
              &Kl[row * 64 + scol]);
    }
    bf16x8 vreg[2];
    #pragma unroll
    for (int r = 0; r < 2; ++r) {
      int row = r * 32 + srow;
      vreg[r] = *(const bf16x8*)&QKV[(rowb + kbase + row) * L + 2048 + h * 64 + scol];
    }
    #pragma unroll
    for (int r = 0; r < 2; ++r) {
      int row = r * 32 + srow;
      #pragma unroll
      for (int j = 0; j < 8; ++j)
        Vt[(scol + j) * 72 + row] = (unsigned short)vreg[r][j];
    }
    __syncthreads();  // staging complete

    // S = Q K^T : per wave 16 q-rows x 64 k-cols
    f32x4 sf[4] = {};
    #pragma unroll
    for (int ks = 0; ks < 2; ++ks) {
      #pragma unroll
      for (int kf = 0; kf < 4; ++kf) {
        bf16x8 kfr = *(const bf16x8*)&Kl[(kf * 16 + lr) * 64 + ks * 32 + lg * 8];
        sf[kf] = __builtin_amdgcn_mfma_f32_16x16x32_bf16(qf[ks], kfr, sf[kf], 0, 0, 0);
      }
    }
    if (kt == qtile) {  // diagonal tile: causal mask (k>q)
      #pragma unroll
      for (int kf = 0; kf < 4; ++kf)
        #pragma unroll
        for (int r = 0; r < 4; ++r) {
          int qq = w * 16 + lg * 4 + r;
          int kk = kf * 16 + lr;
          if (kk > qq) sf[kf][r] = -1e30f;
        }
    }
    // online softmax: rows live across lanes sharing lg; reduce over lr
    float mt[4];
    #pragma unroll
    for (int r = 0; r < 4; ++r)
      mt[r] = fmaxf(fmaxf(sf[0][r], sf[1][r]), fmaxf(sf[2][r], sf[3][r]));
    #pragma unroll
    for (int off = 8; off >= 1; off >>= 1)
      #pragma unroll
      for (int r = 0; r < 4; ++r)
        mt[r] = fmaxf(mt[r], __shfl_xor(mt[r], off, 64));
    #pragma unroll
    for (int r = 0; r < 4; ++r) {
      float mn = fmaxf(m[r], mt[r]);
      float al = exp2f((m[r] - mn) * cexp);
      m[r] = mn;
      lsum[r] *= al;
      #pragma unroll
      for (int j = 0; j < 4; ++j) oacc[j][r] *= al;
    }
    float rs[4] = {0.f, 0.f, 0.f, 0.f};
    #pragma unroll
    for (int kf = 0; kf < 4; ++kf)
      #pragma unroll
      for (int r = 0; r < 4; ++r) {
        float p = exp2f((sf[kf][r] - m[r]) * cexp);
        sf[kf][r] = p;
        rs[r] += p;
      }
    #pragma unroll
    for (int off = 8; off >= 1; off >>= 1)
      #pragma unroll
      for (int r = 0; r < 4; ++r)
        rs[r] += __shfl_xor(rs[r], off, 64);
    #pragma unroll
    for (int r = 0; r < 4; ++r) lsum[r] += rs[r];
    // P -> LDS (wave-private) for A-frag transpose
    #pragma unroll
    for (int kf = 0; kf < 4; ++kf)
      #pragma unroll
      for (int r = 0; r < 4; ++r)
        Pl[w][(lg * 4 + r) * 72 + kf * 16 + lr] = f2bf(sf[kf][r]);
    // O += P V
    #pragma unroll
    for (int ks = 0; ks < 2; ++ks) {
      bf16x8 pf = *(const bf16x8*)&Pl[w][lr * 72 + ks * 32 + lg * 8];
      #pragma unroll
      for (int j = 0; j < 4; ++j) {
        bf16x8 vf = *(const bf16x8*)&Vt[(j * 16 + lr) * 72 + ks * 32 + lg * 8];
        oacc[j] = __builtin_amdgcn_mfma_f32_16x16x32_bf16(pf, vf, oacc[j], 0, 0, 0);
      }
    }
  }
  #pragma unroll
  for (int r = 0; r < 4; ++r) {
    float inv = 1.0f / lsum[r];
    long orow = rowb + qbase + w * 16 + lg * 4 + r;
    #pragma unroll
    for (int j = 0; j < 4; ++j)
      O[orow * 1024 + h * 64 + j * 16 + lr] = f2bf(oacc[j][r] * inv);
  }
}

// ---------------- launch ----------------
extern "C" void kernel_launch(void* const* d_in, const int* in_sizes, int n_in,
                              void* d_out, int out_size, void* d_ws, size_t ws_size,
                              hipStream_t stream) {
  const float* x  = (const float*)d_in[0];
  const float* Wq = (const float*)d_in[1];
  const float* Wk = (const float*)d_in[2];
  const float* Wv = (const float*)d_in[3];
  const float* Wo = (const float*)d_in[4];
  char* ws = (char*)d_ws;
  // workspace layout (48 MiB total)
  unsigned short* xb   = (unsigned short*)(ws);                    // 8 MiB  4096x1024
  unsigned short* Wb   = (unsigned short*)(ws + (8u << 20));       // 6 MiB  3072x1024 (Wq|Wk|Wv)
  unsigned short* Wob  = (unsigned short*)(ws + (14u << 20));      // 2 MiB  1024x1024
  unsigned short* QKVb = (unsigned short*)(ws + (16u << 20));      // 24 MiB 4096x3072
  unsigned short* Ob   = (unsigned short*)(ws + (40u << 20));      // 8 MiB  4096x1024

  cvt_k<<<4096, 256, 0, stream>>>(x, xb, 4096 * 1024 / 4);
  cvt_k<<<1024, 256, 0, stream>>>(Wq, Wb, 1024 * 1024 / 4);
  cvt_k<<<1024, 256, 0, stream>>>(Wk, Wb + 1024 * 1024, 1024 * 1024 / 4);
  cvt_k<<<1024, 256, 0, stream>>>(Wv, Wb + 2 * 1024 * 1024, 1024 * 1024 / 4);
  cvt_k<<<1024, 256, 0, stream>>>(Wo, Wob, 1024 * 1024 / 4);

  // QKV = x @ [Wq|Wk|Wv]^T   (M=4096, N=3072, K=1024)
  gemm_bt<0><<<dim3(32, 24), 256, 0, stream>>>(xb, Wb, QKVb, 3072, 1024);
  // RoPE on Q and K in place
  rope_k<<<(4096 * 512) / 256, 256, 0, stream>>>(QKVb);
  // causal flash attention -> Ob (4096 x 1024 bf16)
  attn_k<<<dim3(32, 32), 256, 0, stream>>>(QKVb, Ob);
  // out = Ob @ Wo^T  (fp32 output)
  gemm_bt<1><<<dim3(32, 8), 256, 0, stream>>>(Ob, Wob, d_out, 1024, 1024);
}

// Round 2
// 268.773 us; speedup vs baseline: 1.0531x; 1.0531x over previous
//
#include <hip/hip_runtime.h>

typedef __attribute__((ext_vector_type(8))) short bf16x8;
typedef __attribute__((ext_vector_type(4))) float f32x4;

typedef const __attribute__((address_space(1))) unsigned int gu32;
typedef __attribute__((address_space(3))) unsigned int lu32;

__device__ __forceinline__ void async16(const void* g, void* l) {
  __builtin_amdgcn_global_load_lds((gu32*)g, (lu32*)l, 16, 0, 0);
}

__device__ __forceinline__ unsigned short f2bf(float f) {
  unsigned int u = __float_as_uint(f);
  u += 0x7fffu + ((u >> 16) & 1u);
  return (unsigned short)(u >> 16);
}
__device__ __forceinline__ float b2f(unsigned short s) {
  return __uint_as_float(((unsigned int)s) << 16);
}

// ---------------- fp32 -> bf16 conversion ----------------
__global__ __launch_bounds__(256) void cvt_k(const float* __restrict__ in,
                                             unsigned short* __restrict__ out,
                                             int n4) {
  int i = blockIdx.x * 256 + threadIdx.x;
  if (i >= n4) return;
  float4 v = ((const float4*)in)[i];
  ushort4 o;
  o.x = f2bf(v.x); o.y = f2bf(v.y); o.z = f2bf(v.z); o.w = f2bf(v.w);
  ((ushort4*)out)[i] = o;
}

// ---------------- GEMM: C[m][n] = sum_k A[m][k] * B[n][k] ----------------
template <int WRITE_F32>
__global__ __launch_bounds__(256) void gemm_bt(const unsigned short* __restrict__ A,
                                               const unsigned short* __restrict__ B,
                                               void* __restrict__ Cp, int N, int K) {
  __shared__ __align__(16) unsigned short Al[128 * 64];
  __shared__ __align__(16) unsigned short Bl[128 * 64];
  const int t = threadIdx.x;
  const int w = t >> 6, l = t & 63;
  const int wm = w >> 1, wn = w & 1;
  const int lr = l & 15, lg = l >> 4;
  const long bm = (long)blockIdx.x * 128, bn = (long)blockIdx.y * 128;
  const int srow = t >> 3, scol = (t & 7) * 8;
  f32x4 acc[4][4] = {};
  for (int k0 = 0; k0 < K; k0 += 64) {
    __syncthreads();
    #pragma unroll
    for (int r = 0; r < 4; ++r) {
      int row = r * 32 + srow;
      async16(&A[(bm + row) * (long)K + k0 + scol], &Al[row * 64 + scol]);
      async16(&B[(bn + row) * (long)K + k0 + scol], &Bl[row * 64 + scol]);
    }
    __syncthreads();
    #pragma unroll
    for (int ks = 0; ks < 2; ++ks) {
      bf16x8 af[4], bf[4];
      #pragma unroll
      for (int i = 0; i < 4; ++i) {
        af[i] = *(const bf16x8*)&Al[(wm * 64 + i * 16 + lr) * 64 + ks * 32 + lg * 8];
        bf[i] = *(const bf16x8*)&Bl[(wn * 64 + i * 16 + lr) * 64 + ks * 32 + lg * 8];
      }
      #pragma unroll
      for (int i = 0; i < 4; ++i)
        #pragma unroll
        for (int j = 0; j < 4; ++j)
          acc[i][j] = __builtin_amdgcn_mfma_f32_16x16x32_bf16(af[i], bf[j], acc[i][j], 0, 0, 0);
    }
  }
  #pragma unroll
  for (int i = 0; i < 4; ++i)
    #pragma unroll
    for (int j = 0; j < 4; ++j)
      #pragma unroll
      for (int r = 0; r < 4; ++r) {
        long row = bm + wm * 64 + i * 16 + lg * 4 + r;
        long col = bn + wn * 64 + j * 16 + lr;
        float v = acc[i][j][r];
        if (WRITE_F32) ((float*)Cp)[row * N + col] = v;
        else ((unsigned short*)Cp)[row * N + col] = f2bf(v);
      }
}

// ---------------- RoPE in-place on Q and K blocks of QKV ----------------
__global__ __launch_bounds__(256) void rope_k(unsigned short* __restrict__ QKV) {
  int idx = blockIdx.x * 256 + threadIdx.x;
  int row = idx >> 9;
  int rem = idx & 511;
  int h = rem >> 5;
  int i = rem & 31;
  int s = row & 2047;
  float invf = exp2f((float)i * (-13.287712379549449f / 32.0f));
  float ang = (float)s * invf;
  float sn, cs;
  sincosf(ang, &sn, &cs);
  size_t base = (size_t)row * 3072 + h * 64 + 2 * i;
  #pragma unroll
  for (int qk = 0; qk < 2; ++qk) {
    size_t off = base + (size_t)qk * 1024;
    float x1 = b2f(QKV[off]);
    float x2 = b2f(QKV[off + 1]);
    QKV[off]     = f2bf(x1 * cs - x2 * sn);
    QKV[off + 1] = f2bf(x1 * sn + x2 * cs);
  }
}

// ---------------- causal flash attention ----------------
// grid: x -> qtile (reversed for LPT), y = b*16+h. 4 waves, 16 q-rows each.
// KV tiles of 64, double-buffered; ONE barrier per iteration.
// All LDS tiles stride-64 with 3-bit XOR column swizzle: element (row, k8*8+e)
// lives at [row*64 + ((k8 ^ (row&7))*8) + e].
__global__ __launch_bounds__(256) void attn_k(const unsigned short* __restrict__ QKV,
                                              unsigned short* __restrict__ O) {
  __shared__ __align__(16) unsigned short Kl[2][64 * 64];   // K tile [k][d] swz
  __shared__ __align__(16) unsigned short Vt[2][64 * 64];   // V^T tile [d][k] swz
  __shared__ __align__(16) unsigned short Pl[4][16 * 64];   // per-wave P [q][k] swz
  const int t = threadIdx.x;
  const int w = t >> 6, l = t & 63;
  const int lr = l & 15, lg = l >> 4;
  const int qtile = 31 - blockIdx.x;   // longest-running blocks launch first
  const int bh = blockIdx.y;
  const int b = bh >> 4, h = bh & 15;
  const int qbase = qtile * 64;
  const long rowb = (long)b * 2048;
  const int L = 3072;
  const int srow = t >> 3;                               // 0..31
  const int scol = (t & 7) * 8;                          // linear LDS col
  const int scolK = ((t & 7) ^ (srow & 7)) * 8;          // swizzled global col

  // Q fragments (held in registers for the whole block)
  bf16x8 qf[2];
  {
    long qrow = rowb + qbase + w * 16 + lr;
    #pragma unroll
    for (int ks = 0; ks < 2; ++ks)
      qf[ks] = *(const bf16x8*)&QKV[qrow * L + h * 64 + ks * 32 + lg * 8];
  }
  float m[4], lsum[4];
  f32x4 oacc[4] = {};
  #pragma unroll
  for (int r = 0; r < 4; ++r) { m[r] = -1e30f; lsum[r] = 0.0f; }
  const float cexp = 0.125f * 1.4426950408889634f;

  bf16x8 vreg[2];
  // ---- prologue: stage tile 0 ----
  {
    const long kb = rowb;  // kt = 0
    #pragma unroll
    for (int r = 0; r < 2; ++r) {
      int row = r * 32 + srow;
      async16(&QKV[(kb + row) * L + 1024 + h * 64 + scolK], &Kl[0][row * 64 + scol]);
      vreg[r] = *(const bf16x8*)&QKV[(kb + row) * L + 2048 + h * 64 + scol];
    }
    #pragma unroll
    for (int r = 0; r < 2; ++r) {
      int row = r * 32 + srow;
      #pragma unroll
      for (int j = 0; j < 8; ++j) {
        int d = scol + j;
        Vt[0][d * 64 + (((row >> 3) ^ (d & 7)) * 8) + (row & 7)] = (unsigned short)vreg[r][j];
      }
    }
  }
  __syncthreads();

  for (int kt = 0; kt <= qtile; ++kt) {
    const int cur = kt & 1, nxt = cur ^ 1;
    const bool pf = (kt < qtile);
    // ---- issue next tile's loads early (overlap with compute) ----
    if (pf) {
      const long kb = rowb + (long)(kt + 1) * 64;
      #pragma unroll
      for (int r = 0; r < 2; ++r) {
        int row = r * 32 + srow;
        async16(&QKV[(kb + row) * L + 1024 + h * 64 + scolK], &Kl[nxt][row * 64 + scol]);
      }
      #pragma unroll
      for (int r = 0; r < 2; ++r)
        vreg[r] = *(const bf16x8*)&QKV[(kb + r * 32 + srow) * L + 2048 + h * 64 + scol];
    }
    // ---- S = Q K^T ----
    f32x4 sf[4] = {};
    __builtin_amdgcn_s_setprio(1);
    #pragma unroll
    for (int ks = 0; ks < 2; ++ks)
      #pragma unroll
      for (int kf = 0; kf < 4; ++kf) {
        int row = kf * 16 + lr;
        bf16x8 kfr = *(const bf16x8*)&Kl[cur][row * 64 + (((ks * 4 + lg) ^ (row & 7)) * 8)];
        sf[kf] = __builtin_amdgcn_mfma_f32_16x16x32_bf16(qf[ks], kfr, sf[kf], 0, 0, 0);
      }
    __builtin_amdgcn_s_setprio(0);
    if (kt == qtile) {
      #pragma unroll
      for (int kf = 0; kf < 4; ++kf)
        #pragma unroll
        for (int r = 0; r < 4; ++r) {
          int qq = w * 16 + lg * 4 + r;
          int kk = kf * 16 + lr;
          if (kk > qq) sf[kf][r] = -1e30f;
        }
    }
    // ---- online softmax (reduce over lr) ----
    float mt[4];
    #pragma unroll
    for (int r = 0; r < 4; ++r)
      mt[r] = fmaxf(fmaxf(sf[0][r], sf[1][r]), fmaxf(sf[2][r], sf[3][r]));
    #pragma unroll
    for (int off = 8; off >= 1; off >>= 1)
      #pragma unroll
      for (int r = 0; r < 4; ++r)
        mt[r] = fmaxf(mt[r], __shfl_xor(mt[r], off, 64));
    #pragma unroll
    for (int r = 0; r < 4; ++r) {
      float mn = fmaxf(m[r], mt[r]);
      float al = exp2f((m[r] - mn) * cexp);
      m[r] = mn;
      lsum[r] *= al;
      #pragma unroll
      for (int j = 0; j < 4; ++j) oacc[j][r] *= al;
    }
    float rs[4] = {0.f, 0.f, 0.f, 0.f};
    #pragma unroll
    for (int kf = 0; kf < 4; ++kf)
      #pragma unroll
      for (int r = 0; r < 4; ++r) {
        float p = exp2f((sf[kf][r] - m[r]) * cexp);
        sf[kf][r] = p;
        rs[r] += p;
      }
    #pragma unroll
    for (int off = 8; off >= 1; off >>= 1)
      #pragma unroll
      for (int r = 0; r < 4; ++r)
        rs[r] += __shfl_xor(rs[r], off, 64);
    #pragma unroll
    for (int r = 0; r < 4; ++r) lsum[r] += rs[r];
    // ---- P -> LDS (wave-private, swizzled) ----
    #pragma unroll
    for (int kf = 0; kf < 4; ++kf)
      #pragma unroll
      for (int r = 0; r < 4; ++r) {
        int prow = lg * 4 + r;
        int c8 = (kf * 2 + (lr >> 3)) ^ (prow & 7);
        Pl[w][prow * 64 + c8 * 8 + (lr & 7)] = f2bf(sf[kf][r]);
      }
    // ---- O += P V ----
    __builtin_amdgcn_s_setprio(1);
    #pragma unroll
    for (int ks = 0; ks < 2; ++ks) {
      bf16x8 pf2 = *(const bf16x8*)&Pl[w][lr * 64 + (((ks * 4 + lg) ^ (lr & 7)) * 8)];
      #pragma unroll
      for (int j = 0; j < 4; ++j) {
        int vrow = j * 16 + lr;
        bf16x8 vf = *(const bf16x8*)&Vt[cur][vrow * 64 + (((ks * 4 + lg) ^ (vrow & 7)) * 8)];
        oacc[j] = __builtin_amdgcn_mfma_f32_16x16x32_bf16(pf2, vf, oacc[j], 0, 0, 0);
      }
    }
    __builtin_amdgcn_s_setprio(0);
    // ---- write next tile's V^T into the other buffer ----
    if (pf) {
      #pragma unroll
      for (int r = 0; r < 2; ++r) {
        int row = r * 32 + srow;
        #pragma unroll
        for (int j = 0; j < 8; ++j) {
          int d = scol + j;
          Vt[nxt][d * 64 + (((row >> 3) ^ (d & 7)) * 8) + (row & 7)] = (unsigned short)vreg[r][j];
        }
      }
    }
    __syncthreads();  // single barrier: orders staging (K async + V scatter) vs next reads
  }
  #pragma unroll
  for (int r = 0; r < 4; ++r) {
    float inv = 1.0f / lsum[r];
    long orow = rowb + qbase + w * 16 + lg * 4 + r;
    #pragma unroll
    for (int j = 0; j < 4; ++j)
      O[orow * 1024 + h * 64 + j * 16 + lr] = f2bf(oacc[j][r] * inv);
  }
}

// ---------------- launch ----------------
extern "C" void kernel_launch(void* const* d_in, const int* in_sizes, int n_in,
                              void* d_out, int out_size, void* d_ws, size_t ws_size,
                              hipStream_t stream) {
  const float* x  = (const float*)d_in[0];
  const float* Wq = (const float*)d_in[1];
  const float* Wk = (const float*)d_in[2];
  const float* Wv = (const float*)d_in[3];
  const float* Wo = (const float*)d_in[4];
  char* ws = (char*)d_ws;
  unsigned short* xb   = (unsigned short*)(ws);                    // 8 MiB
  unsigned short* Wb   = (unsigned short*)(ws + (8u << 20));       // 6 MiB
  unsigned short* Wob  = (unsigned short*)(ws + (14u << 20));      // 2 MiB
  unsigned short* QKVb = (unsigned short*)(ws + (16u << 20));      // 24 MiB
  unsigned short* Ob   = (unsigned short*)(ws + (40u << 20));      // 8 MiB

  cvt_k<<<4096, 256, 0, stream>>>(x, xb, 4096 * 1024 / 4);
  cvt_k<<<1024, 256, 0, stream>>>(Wq, Wb, 1024 * 1024 / 4);
  cvt_k<<<1024, 256, 0, stream>>>(Wk, Wb + 1024 * 1024, 1024 * 1024 / 4);
  cvt_k<<<1024, 256, 0, stream>>>(Wv, Wb + 2 * 1024 * 1024, 1024 * 1024 / 4);
  cvt_k<<<1024, 256, 0, stream>>>(Wo, Wob, 1024 * 1024 / 4);

  gemm_bt<0><<<dim3(32, 24), 256, 0, stream>>>(xb, Wb, QKVb, 3072, 1024);
  rope_k<<<(4096 * 512) / 256, 256, 0, stream>>>(QKVb);
  attn_k<<<dim3(32, 32), 256, 0, stream>>>(QKVb, Ob);
  gemm_bt<1><<<dim3(32, 8), 256, 0, stream>>>(Ob, Wob, d_out, 1024, 1024);
}

// Round 3
// 179.507 us; speedup vs baseline: 1.5767x; 1.4973x over previous
//
#include <hip/hip_runtime.h>

typedef __attribute__((ext_vector_type(8))) short bf16x8;
typedef __attribute__((ext_vector_type(4))) float f32x4;
typedef __attribute__((ext_vector_type(16))) float f32x16;

typedef const __attribute__((address_space(1))) unsigned int gu32;
typedef __attribute__((address_space(3))) unsigned int lu32;

__device__ __forceinline__ void async16(const void* g, void* l) {
  __builtin_amdgcn_global_load_lds((gu32*)g, (lu32*)l, 16, 0, 0);
}

__device__ __forceinline__ unsigned short f2bf(float f) {
  unsigned int u = __float_as_uint(f);
  u += 0x7fffu + ((u >> 16) & 1u);
  return (unsigned short)(u >> 16);
}
__device__ __forceinline__ float b2f(unsigned short s) {
  return __uint_as_float(((unsigned int)s) << 16);
}
__device__ __forceinline__ unsigned int cvtpk(float lo, float hi) {
  unsigned int w;
  asm("v_cvt_pk_bf16_f32 %0, %1, %2" : "=v"(w) : "v"(lo), "v"(hi));
  return w;
}
// swaps upper 32 lanes of x with lower 32 lanes of y (both updated)
__device__ __forceinline__ void plswap(unsigned int& x, unsigned int& y) {
  asm("v_permlane32_swap_b32 %0, %1" : "+v"(x), "+v"(y));
}

// ---------------- fp32 -> bf16 conversion ----------------
__global__ __launch_bounds__(256) void cvt_k(const float* __restrict__ in,
                                             unsigned short* __restrict__ out,
                                             int n4) {
  int i = blockIdx.x * 256 + threadIdx.x;
  if (i >= n4) return;
  float4 v = ((const float4*)in)[i];
  ushort4 o;
  o.x = f2bf(v.x); o.y = f2bf(v.y); o.z = f2bf(v.z); o.w = f2bf(v.w);
  ((ushort4*)out)[i] = o;
}

// ---------------- GEMM: C[m][n] = sum_k A[m][k] * B[n][k] ----------------
template <int WRITE_F32>
__global__ __launch_bounds__(256) void gemm_bt(const unsigned short* __restrict__ A,
                                               const unsigned short* __restrict__ B,
                                               void* __restrict__ Cp, int N, int K) {
  __shared__ __align__(16) unsigned short Al[128 * 64];
  __shared__ __align__(16) unsigned short Bl[128 * 64];
  const int t = threadIdx.x;
  const int w = t >> 6, l = t & 63;
  const int wm = w >> 1, wn = w & 1;
  const int lr = l & 15, lg = l >> 4;
  const long bm = (long)blockIdx.x * 128, bn = (long)blockIdx.y * 128;
  const int srow = t >> 3, scol = (t & 7) * 8;
  f32x4 acc[4][4] = {};
  for (int k0 = 0; k0 < K; k0 += 64) {
    __syncthreads();
    #pragma unroll
    for (int r = 0; r < 4; ++r) {
      int row = r * 32 + srow;
      async16(&A[(bm + row) * (long)K + k0 + scol], &Al[row * 64 + scol]);
      async16(&B[(bn + row) * (long)K + k0 + scol], &Bl[row * 64 + scol]);
    }
    __syncthreads();
    #pragma unroll
    for (int ks = 0; ks < 2; ++ks) {
      bf16x8 af[4], bf[4];
      #pragma unroll
      for (int i = 0; i < 4; ++i) {
        af[i] = *(const bf16x8*)&Al[(wm * 64 + i * 16 + lr) * 64 + ks * 32 + lg * 8];
        bf[i] = *(const bf16x8*)&Bl[(wn * 64 + i * 16 + lr) * 64 + ks * 32 + lg * 8];
      }
      #pragma unroll
      for (int i = 0; i < 4; ++i)
        #pragma unroll
        for (int j = 0; j < 4; ++j)
          acc[i][j] = __builtin_amdgcn_mfma_f32_16x16x32_bf16(af[i], bf[j], acc[i][j], 0, 0, 0);
    }
  }
  #pragma unroll
  for (int i = 0; i < 4; ++i)
    #pragma unroll
    for (int j = 0; j < 4; ++j)
      #pragma unroll
      for (int r = 0; r < 4; ++r) {
        long row = bm + wm * 64 + i * 16 + lg * 4 + r;
        long col = bn + wn * 64 + j * 16 + lr;
        float v = acc[i][j][r];
        if (WRITE_F32) ((float*)Cp)[row * N + col] = v;
        else ((unsigned short*)Cp)[row * N + col] = f2bf(v);
      }
}

// ---------------- RoPE in-place on Q and K blocks of QKV ----------------
__global__ __launch_bounds__(256) void rope_k(unsigned short* __restrict__ QKV) {
  int idx = blockIdx.x * 256 + threadIdx.x;
  int row = idx >> 9;
  int rem = idx & 511;
  int h = rem >> 5;
  int i = rem & 31;
  int s = row & 2047;
  float invf = exp2f((float)i * (-13.287712379549449f / 32.0f));
  float ang = (float)s * invf;
  float sn, cs;
  sincosf(ang, &sn, &cs);
  size_t base = (size_t)row * 3072 + h * 64 + 2 * i;
  #pragma unroll
  for (int qk = 0; qk < 2; ++qk) {
    size_t off = base + (size_t)qk * 1024;
    float x1 = b2f(QKV[off]);
    float x2 = b2f(QKV[off + 1]);
    QKV[off]     = f2bf(x1 * cs - x2 * sn);
    QKV[off + 1] = f2bf(x1 * sn + x2 * cs);
  }
}

// ---------------- causal flash attention, swapped-QK^T 32x32 structure ----
// grid: x -> qtile of 128 rows (reversed, LPT), y = b*16+h. 256 thr / 4 waves.
// Wave w owns 32 q-rows: q = Qb + 32w + (lane&31); lane&31 = q, hi = lane>>5.
// S^T = mfma32x32x16(A=K, B=Q): lane holds P[q][k=crow(r,hi)+32*kt2],
// crow(r,hi) = (r&3)+8*(r>>2)+4*hi. Softmax in-register (31 fmax + 1 shfl).
// PV computes O^T = mfma(A=V^T, B=P): lane holds O[q][d=32dt+crow(r,hi)].
// P B-frag built via v_cvt_pk_bf16_f32 + v_permlane32_swap_b32.
__global__ __launch_bounds__(256, 2) void attn_k(const unsigned short* __restrict__ QKV,
                                                 unsigned short* __restrict__ O) {
  __shared__ __align__(16) unsigned short Kl[2][64 * 64];   // K tile [k][d], swz
  __shared__ __align__(16) unsigned short Vt[2][64 * 64];   // V^T tile [d][k], swz
  const int t = threadIdx.x;
  const int w = t >> 6, l = t & 63;
  const int q31 = l & 31, hi = l >> 5;
  const int qt = 15 - (int)blockIdx.x;     // LPT
  const int bh = blockIdx.y;
  const int b = bh >> 4, h = bh & 15;
  const int Qb = qt * 128;
  const long rowb = (long)b * 2048;
  const int L = 3072;
  const int NT = 2 * qt + 2;               // KV tiles this block stages
  const int srow = t >> 3;                 // 0..31
  const int scol = (t & 7) * 8;
  const int scolK = ((t & 7) ^ (srow & 7)) * 8;
  const float cexp = 0.125f * 1.4426950408889634f;

  const int qmy = Qb + 32 * w + q31;       // my q row (0..2047)
  const long qgrow = rowb + qmy;
  const int ktmax = (Qb + 32 * w) >> 6;    // wave-uniform last useful tile

  // Q fragments: lane holds Q[qmy][16dk + 8hi .. +8]
  bf16x8 qf[4];
  #pragma unroll
  for (int dk = 0; dk < 4; ++dk)
    qf[dk] = *(const bf16x8*)&QKV[qgrow * L + h * 64 + dk * 16 + hi * 8];

  float m_ = -1e30f, ls = 0.0f;
  f32x16 oa[2];
  #pragma unroll
  for (int dt = 0; dt < 2; ++dt)
    #pragma unroll
    for (int r = 0; r < 16; ++r) oa[dt][r] = 0.0f;

  // ---- prologue: stage tile 0 ----
  {
    #pragma unroll
    for (int r = 0; r < 2; ++r) {
      int row = r * 32 + srow;
      async16(&QKV[(rowb + row) * L + 1024 + h * 64 + scolK], &Kl[0][row * 64 + scol]);
      bf16x8 v0 = *(const bf16x8*)&QKV[(rowb + row) * L + 2048 + h * 64 + scol];
      #pragma unroll
      for (int j = 0; j < 8; ++j) {
        int d = scol + j;
        Vt[0][d * 64 + (((row >> 3) ^ (d & 7)) * 8) + (row & 7)] = (unsigned short)v0[j];
      }
    }
  }
  __syncthreads();

  for (int kt = 0; kt < NT; ++kt) {
    const int cur = kt & 1, nxt = cur ^ 1;
    const bool pfj = (kt + 1 < NT);
    bf16x8 vreg[2];
    if (pfj) {
      const long kb = rowb + (long)(kt + 1) * 64;
      #pragma unroll
      for (int r = 0; r < 2; ++r) {
        int row = r * 32 + srow;
        async16(&QKV[(kb + row) * L + 1024 + h * 64 + scolK], &Kl[nxt][row * 64 + scol]);
        vreg[r] = *(const bf16x8*)&QKV[(kb + row) * L + 2048 + h * 64 + scol];
      }
    }
    if (kt <= ktmax) {
      // ---- S^T = K Q^T ----
      f32x16 st[2];
      #pragma unroll
      for (int kt2 = 0; kt2 < 2; ++kt2)
        #pragma unroll
        for (int r = 0; r < 16; ++r) st[kt2][r] = 0.0f;
      __builtin_amdgcn_s_setprio(1);
      #pragma unroll
      for (int dk = 0; dk < 4; ++dk)
        #pragma unroll
        for (int kt2 = 0; kt2 < 2; ++kt2) {
          int krow = kt2 * 32 + q31;
          bf16x8 kfr = *(const bf16x8*)&Kl[cur][krow * 64 + (((2 * dk + hi) ^ (krow & 7)) * 8)];
          st[kt2] = __builtin_amdgcn_mfma_f32_32x32x16_bf16(kfr, qf[dk], st[kt2], 0, 0, 0);
        }
      __builtin_amdgcn_s_setprio(0);
      // ---- causal mask (diagonal tile only) ----
      if (kt == ktmax) {
        #pragma unroll
        for (int kt2 = 0; kt2 < 2; ++kt2)
          #pragma unroll
          for (int r = 0; r < 16; ++r) {
            int kg = kt * 64 + kt2 * 32 + (r & 3) + 8 * (r >> 2) + 4 * hi;
            if (kg > qmy) st[kt2][r] = -1e30f;
          }
      }
      // ---- online softmax, in-register ----
      float mt = st[0][0];
      #pragma unroll
      for (int kt2 = 0; kt2 < 2; ++kt2)
        #pragma unroll
        for (int r = 0; r < 16; ++r) mt = fmaxf(mt, st[kt2][r]);
      mt = fmaxf(mt, __shfl_xor(mt, 32, 64));
      if (__any((mt - m_) * cexp > 8.0f)) {   // defer-max (T13)
        float mn = fmaxf(m_, mt);
        float al = exp2f((m_ - mn) * cexp);
        m_ = mn;
        ls *= al;
        #pragma unroll
        for (int dt = 0; dt < 2; ++dt)
          #pragma unroll
          for (int r = 0; r < 16; ++r) oa[dt][r] *= al;
      }
      const float mc = m_ * cexp;
      float rs = 0.0f;
      #pragma unroll
      for (int kt2 = 0; kt2 < 2; ++kt2)
        #pragma unroll
        for (int r = 0; r < 16; ++r) {
          float p = exp2f(st[kt2][r] * cexp - mc);
          st[kt2][r] = p;
          rs += p;
        }
      rs += __shfl_xor(rs, 32, 64);
      ls += rs;
      // ---- pack P into PV B-frags: lane needs P[q][16ks+8hi+j], j=0..7 ----
      bf16x8 pfr[4];
      #pragma unroll
      for (int ks = 0; ks < 4; ++ks) {
        int tt = ks >> 1, gX = 2 * (ks & 1), gY = gX + 1;
        unsigned int x1 = cvtpk(st[tt][4 * gX + 0], st[tt][4 * gX + 1]);
        unsigned int y1 = cvtpk(st[tt][4 * gY + 0], st[tt][4 * gY + 1]);
        plswap(x1, y1);
        unsigned int x2 = cvtpk(st[tt][4 * gX + 2], st[tt][4 * gX + 3]);
        unsigned int y2 = cvtpk(st[tt][4 * gY + 2], st[tt][4 * gY + 3]);
        plswap(x2, y2);
        union { unsigned int u[4]; bf16x8 b; } cc;
        cc.u[0] = x1; cc.u[1] = x2; cc.u[2] = y1; cc.u[3] = y2;
        pfr[ks] = cc.b;
      }
      // ---- O^T += V^T P ----
      __builtin_amdgcn_s_setprio(1);
      #pragma unroll
      for (int dt = 0; dt < 2; ++dt)
        #pragma unroll
        for (int ks = 0; ks < 4; ++ks) {
          int vrow = dt * 32 + q31;
          bf16x8 vf = *(const bf16x8*)&Vt[cur][vrow * 64 + (((2 * ks + hi) ^ (vrow & 7)) * 8)];
          oa[dt] = __builtin_amdgcn_mfma_f32_32x32x16_bf16(vf, pfr[ks], oa[dt], 0, 0, 0);
        }
      __builtin_amdgcn_s_setprio(0);
    }
    // ---- scatter next V^T ----
    if (pfj) {
      #pragma unroll
      for (int r = 0; r < 2; ++r) {
        int row = r * 32 + srow;
        #pragma unroll
        for (int j = 0; j < 8; ++j) {
          int d = scol + j;
          Vt[nxt][d * 64 + (((row >> 3) ^ (d & 7)) * 8) + (row & 7)] = (unsigned short)vreg[r][j];
        }
      }
    }
    __syncthreads();
  }
  // ---- epilogue: O[qmy][d], d = 32dt + (r&3) + 8(r>>2) + 4hi ----
  float inv = 1.0f / ls;
  #pragma unroll
  for (int dt = 0; dt < 2; ++dt)
    #pragma unroll
    for (int g = 0; g < 4; ++g) {
      ushort4 o4;
      o4.x = f2bf(oa[dt][4 * g + 0] * inv);
      o4.y = f2bf(oa[dt][4 * g + 1] * inv);
      o4.z = f2bf(oa[dt][4 * g + 2] * inv);
      o4.w = f2bf(oa[dt][4 * g + 3] * inv);
      *(ushort4*)&O[qgrow * 1024 + h * 64 + dt * 32 + 8 * g + 4 * hi] = o4;
    }
}

// ---------------- launch ----------------
extern "C" void kernel_launch(void* const* d_in, const int* in_sizes, int n_in,
                              void* d_out, int out_size, void* d_ws, size_t ws_size,
                              hipStream_t stream) {
  const float* x  = (const float*)d_in[0];
  const float* Wq = (const float*)d_in[1];
  const float* Wk = (const float*)d_in[2];
  const float* Wv = (const float*)d_in[3];
  const float* Wo = (const float*)d_in[4];
  char* ws = (char*)d_ws;
  unsigned short* xb   = (unsigned short*)(ws);                    // 8 MiB
  unsigned short* Wb   = (unsigned short*)(ws + (8u << 20));       // 6 MiB
  unsigned short* Wob  = (unsigned short*)(ws + (14u << 20));      // 2 MiB
  unsigned short* QKVb = (unsigned short*)(ws + (16u << 20));      // 24 MiB
  unsigned short* Ob   = (unsigned short*)(ws + (40u << 20));      // 8 MiB

  cvt_k<<<4096, 256, 0, stream>>>(x, xb, 4096 * 1024 / 4);
  cvt_k<<<1024, 256, 0, stream>>>(Wq, Wb, 1024 * 1024 / 4);
  cvt_k<<<1024, 256, 0, stream>>>(Wk, Wb + 1024 * 1024, 1024 * 1024 / 4);
  cvt_k<<<1024, 256, 0, stream>>>(Wv, Wb + 2 * 1024 * 1024, 1024 * 1024 / 4);
  cvt_k<<<1024, 256, 0, stream>>>(Wo, Wob, 1024 * 1024 / 4);

  gemm_bt<0><<<dim3(32, 24), 256, 0, stream>>>(xb, Wb, QKVb, 3072, 1024);
  rope_k<<<(4096 * 512) / 256, 256, 0, stream>>>(QKVb);
  attn_k<<<dim3(16, 32), 256, 0, stream>>>(QKVb, Ob);
  gemm_bt<1><<<dim3(32, 8), 256, 0, stream>>>(Ob, Wob, d_out, 1024, 1024);
}

// Round 6
// 165.693 us; speedup vs baseline: 1.7082x; 1.0834x over previous
//
#include <hip/hip_runtime.h>

typedef __attribute__((ext_vector_type(8))) short bf16x8;
typedef __attribute__((ext_vector_type(4))) float f32x4;
typedef __attribute__((ext_vector_type(16))) float f32x16;

typedef const __attribute__((address_space(1))) unsigned int gu32;
typedef __attribute__((address_space(3))) unsigned int lu32;

__device__ __forceinline__ void async16(const void* g, void* l) {
  __builtin_amdgcn_global_load_lds((gu32*)g, (lu32*)l, 16, 0, 0);
}

__device__ __forceinline__ unsigned short f2bf(float f) {
  unsigned int u = __float_as_uint(f);
  u += 0x7fffu + ((u >> 16) & 1u);
  return (unsigned short)(u >> 16);
}
__device__ __forceinline__ float b2f(unsigned short s) {
  return __uint_as_float(((unsigned int)s) << 16);
}
__device__ __forceinline__ unsigned int cvtpk(float lo, float hi) {
  unsigned int w;
  asm("v_cvt_pk_bf16_f32 %0, %1, %2" : "=v"(w) : "v"(lo), "v"(hi));
  return w;
}
__device__ __forceinline__ void plswap(unsigned int& x, unsigned int& y) {
  asm("v_permlane32_swap_b32 %0, %1" : "+v"(x), "+v"(y));
}

// ---------------- fp32 -> bf16 conversion ----------------
__global__ __launch_bounds__(256) void cvt_k(const float* __restrict__ in,
                                             unsigned short* __restrict__ out,
                                             int n4) {
  int i = blockIdx.x * 256 + threadIdx.x;
  if (i >= n4) return;
  float4 v = ((const float4*)in)[i];
  ushort4 o;
  o.x = f2bf(v.x); o.y = f2bf(v.y); o.z = f2bf(v.z); o.w = f2bf(v.w);
  ((ushort4*)out)[i] = o;
}

// ---------------- GEMM: C[m][n] = sum_k A[m][k] * B[n][k] ----------------
template <int WRITE_F32>
__global__ __launch_bounds__(256) void gemm_bt(const unsigned short* __restrict__ A,
                                               const unsigned short* __restrict__ B,
                                               void* __restrict__ Cp, int N, int K) {
  __shared__ __align__(16) unsigned short Al[128 * 64];
  __shared__ __align__(16) unsigned short Bl[128 * 64];
  const int t = threadIdx.x;
  const int w = t >> 6, l = t & 63;
  const int wm = w >> 1, wn = w & 1;
  const int lr = l & 15, lg = l >> 4;
  const long bm = (long)blockIdx.x * 128, bn = (long)blockIdx.y * 128;
  const int srow = t >> 3, scol = (t & 7) * 8;
  f32x4 acc[4][4] = {};
  for (int k0 = 0; k0 < K; k0 += 64) {
    __syncthreads();
    #pragma unroll
    for (int r = 0; r < 4; ++r) {
      int row = r * 32 + srow;
      async16(&A[(bm + row) * (long)K + k0 + scol], &Al[row * 64 + scol]);
      async16(&B[(bn + row) * (long)K + k0 + scol], &Bl[row * 64 + scol]);
    }
    __syncthreads();
    #pragma unroll
    for (int ks = 0; ks < 2; ++ks) {
      bf16x8 af[4], bf[4];
      #pragma unroll
      for (int i = 0; i < 4; ++i) {
        af[i] = *(const bf16x8*)&Al[(wm * 64 + i * 16 + lr) * 64 + ks * 32 + lg * 8];
        bf[i] = *(const bf16x8*)&Bl[(wn * 64 + i * 16 + lr) * 64 + ks * 32 + lg * 8];
      }
      #pragma unroll
      for (int i = 0; i < 4; ++i)
        #pragma unroll
        for (int j = 0; j < 4; ++j)
          acc[i][j] = __builtin_amdgcn_mfma_f32_16x16x32_bf16(af[i], bf[j], acc[i][j], 0, 0, 0);
    }
  }
  #pragma unroll
  for (int i = 0; i < 4; ++i)
    #pragma unroll
    for (int j = 0; j < 4; ++j)
      #pragma unroll
      for (int r = 0; r < 4; ++r) {
        long row = bm + wm * 64 + i * 16 + lg * 4 + r;
        long col = bn + wn * 64 + j * 16 + lr;
        float v = acc[i][j][r];
        if (WRITE_F32) ((float*)Cp)[row * N + col] = v;
        else ((unsigned short*)Cp)[row * N + col] = f2bf(v);
      }
}

// ---------------- RoPE in-place on Q and K blocks of QKV ----------------
__global__ __launch_bounds__(256) void rope_k(unsigned short* __restrict__ QKV) {
  int idx = blockIdx.x * 256 + threadIdx.x;
  int row = idx >> 9;
  int rem = idx & 511;
  int h = rem >> 5;
  int i = rem & 31;
  int s = row & 2047;
  float invf = exp2f((float)i * (-13.287712379549449f / 32.0f));
  float ang = (float)s * invf;
  float sn, cs;
  sincosf(ang, &sn, &cs);
  size_t base = (size_t)row * 3072 + h * 64 + 2 * i;
  #pragma unroll
  for (int qk = 0; qk < 2; ++qk) {
    size_t off = base + (size_t)qk * 1024;
    float x1 = b2f(QKV[off]);
    float x2 = b2f(QKV[off + 1]);
    QKV[off]     = f2bf(x1 * cs - x2 * sn);
    QKV[off + 1] = f2bf(x1 * sn + x2 * cs);
  }
}

// ---------------- V transpose: QKV V-part -> Vt[bh][d=64][k=2048] ----------
__global__ __launch_bounds__(256) void vtr_k(const unsigned short* __restrict__ QKV,
                                             unsigned short* __restrict__ Vt) {
  __shared__ unsigned short tl[64][66];
  const int kt = blockIdx.x;            // k-tile 0..31
  const int bh = blockIdx.y;            // 0..31
  const int b = bh >> 4, h = bh & 15;
  const int t = threadIdx.x;
  const int row = t >> 3, c8 = t & 7;
  #pragma unroll
  for (int r = 0; r < 2; ++r) {
    int k = r * 32 + row;
    bf16x8 v = *(const bf16x8*)&QKV[((long)b * 2048 + kt * 64 + k) * 3072 + 2048 + h * 64 + c8 * 8];
    #pragma unroll
    for (int j = 0; j < 8; ++j) tl[c8 * 8 + j][k] = (unsigned short)v[j];
  }
  __syncthreads();
  #pragma unroll
  for (int r = 0; r < 2; ++r) {
    int d = r * 32 + row;
    ushort4 a, bq;
    a.x = tl[d][c8 * 8 + 0]; a.y = tl[d][c8 * 8 + 1];
    a.z = tl[d][c8 * 8 + 2]; a.w = tl[d][c8 * 8 + 3];
    bq.x = tl[d][c8 * 8 + 4]; bq.y = tl[d][c8 * 8 + 5];
    bq.z = tl[d][c8 * 8 + 6]; bq.w = tl[d][c8 * 8 + 7];
    long off = ((long)bh * 64 + d) * 2048 + kt * 64 + c8 * 8;
    *(ushort4*)&Vt[off] = a;
    *(ushort4*)&Vt[off + 4] = bq;
  }
}

// ---------------- causal flash attention ----------------
// 64 q-rows/block, 2 waves (32 rows each), 128 threads. Swapped-QK^T 32x32;
// K and V^T both staged row-major via global_load_lds with XOR column swizzle
// (proven R3 mechanics). Double-buffered, one __syncthreads per KV tile.
__global__ __launch_bounds__(128, 4) void attn_k(const unsigned short* __restrict__ QKV,
                                                 const unsigned short* __restrict__ VtG,
                                                 unsigned short* __restrict__ O) {
  __shared__ __align__(16) unsigned short Kl[2][64 * 64];   // K tile [k][d], swz
  __shared__ __align__(16) unsigned short Vl[2][64 * 64];   // V^T tile [d][k], swz
  const int t = threadIdx.x;
  const int w = t >> 6, l = t & 63;
  const int q31 = l & 31, hi = l >> 5;
  const int qt = 31 - (int)blockIdx.x;     // LPT: longest first
  const int bh = blockIdx.y;
  const int b = bh >> 4, h = bh & 15;
  const int Qb = qt * 64;
  const long rowb = (long)b * 2048;
  const int L = 3072;
  const int NT = qt + 1;
  const int srow = t >> 3;                 // 0..15
  const int scol = (t & 7) * 8;
  const int scolK = ((t & 7) ^ (srow & 7)) * 8;
  const float cexp = 0.125f * 1.4426950408889634f;

  const int qmy = Qb + 32 * w + q31;
  const long qgrow = rowb + qmy;

  // Q fragments: lane holds Q[qmy][16dk + 8hi + 0..7]
  bf16x8 qf[4];
  #pragma unroll
  for (int dk = 0; dk < 4; ++dk)
    qf[dk] = *(const bf16x8*)&QKV[qgrow * L + h * 64 + dk * 16 + hi * 8];

  float m_ = -1e30f, ls = 0.0f;
  f32x16 oa[2];
  #pragma unroll
  for (int dt = 0; dt < 2; ++dt)
    #pragma unroll
    for (int r = 0; r < 16; ++r) oa[dt][r] = 0.0f;

  auto STAGE = [&](int ts) {
    const int bi = ts & 1;
    const long kb = rowb + (long)ts * 64;
    const long vrowb = (long)bh * 64;
    #pragma unroll
    for (int r = 0; r < 4; ++r) {
      int row = r * 16 + srow;
      async16(&QKV[(kb + row) * L + 1024 + h * 64 + scolK], &Kl[bi][row * 64 + scol]);
      async16(&VtG[(vrowb + row) * 2048 + ts * 64 + scolK], &Vl[bi][row * 64 + scol]);
    }
  };

  STAGE(0);
  __syncthreads();   // tile 0 resident

  for (int kt = 0; kt < NT; ++kt) {
    const int cur = kt & 1;
    if (kt + 1 < NT) STAGE(kt + 1);   // prefetch into other buffer

    // ---- S^T = K Q^T ----
    f32x16 st[2];
    #pragma unroll
    for (int kt2 = 0; kt2 < 2; ++kt2)
      #pragma unroll
      for (int r = 0; r < 16; ++r) st[kt2][r] = 0.0f;
    __builtin_amdgcn_s_setprio(1);
    #pragma unroll
    for (int dk = 0; dk < 4; ++dk)
      #pragma unroll
      for (int kt2 = 0; kt2 < 2; ++kt2) {
        int krow = kt2 * 32 + q31;
        bf16x8 kfr = *(const bf16x8*)&Kl[cur][krow * 64 + (((2 * dk + hi) ^ (krow & 7)) * 8)];
        st[kt2] = __builtin_amdgcn_mfma_f32_32x32x16_bf16(kfr, qf[dk], st[kt2], 0, 0, 0);
      }
    __builtin_amdgcn_s_setprio(0);
    // ---- causal mask (diagonal tile only) ----
    if (kt == NT - 1) {
      #pragma unroll
      for (int kt2 = 0; kt2 < 2; ++kt2)
        #pragma unroll
        for (int r = 0; r < 16; ++r) {
          int kg = kt * 64 + kt2 * 32 + (r & 3) + 8 * (r >> 2) + 4 * hi;
          if (kg > qmy) st[kt2][r] = -1e30f;
        }
    }
    // ---- online softmax, tree reductions ----
    float m0[8];
    #pragma unroll
    for (int i = 0; i < 8; ++i)
      m0[i] = fmaxf(fmaxf(st[0][i], st[0][i + 8]), fmaxf(st[1][i], st[1][i + 8]));
    float mt = fmaxf(fmaxf(fmaxf(m0[0], m0[1]), fmaxf(m0[2], m0[3])),
                     fmaxf(fmaxf(m0[4], m0[5]), fmaxf(m0[6], m0[7])));
    mt = fmaxf(mt, __shfl_xor(mt, 32, 64));
    if (__any((mt - m_) * cexp > 8.0f)) {   // defer-max (T13)
      float mn = fmaxf(m_, mt);
      float al = __builtin_amdgcn_exp2f((m_ - mn) * cexp);
      m_ = mn;
      ls *= al;
      #pragma unroll
      for (int dt = 0; dt < 2; ++dt)
        #pragma unroll
        for (int r = 0; r < 16; ++r) oa[dt][r] *= al;
    }
    const float mc = m_ * cexp;
    #pragma unroll
    for (int kt2 = 0; kt2 < 2; ++kt2)
      #pragma unroll
      for (int r = 0; r < 16; ++r)
        st[kt2][r] = __builtin_amdgcn_exp2f(fmaf(st[kt2][r], cexp, -mc));
    float s0[8];
    #pragma unroll
    for (int i = 0; i < 8; ++i)
      s0[i] = (st[0][i] + st[0][i + 8]) + (st[1][i] + st[1][i + 8]);
    float rs = ((s0[0] + s0[1]) + (s0[2] + s0[3])) + ((s0[4] + s0[5]) + (s0[6] + s0[7]));
    rs += __shfl_xor(rs, 32, 64);
    ls += rs;
    // ---- pack P into PV B-frags via cvt_pk + permlane32_swap ----
    bf16x8 pfr[4];
    #pragma unroll
    for (int ks = 0; ks < 4; ++ks) {
      int tt = ks >> 1, gX = 2 * (ks & 1), gY = gX + 1;
      unsigned int x1 = cvtpk(st[tt][4 * gX + 0], st[tt][4 * gX + 1]);
      unsigned int y1 = cvtpk(st[tt][4 * gY + 0], st[tt][4 * gY + 1]);
      plswap(x1, y1);
      unsigned int x2 = cvtpk(st[tt][4 * gX + 2], st[tt][4 * gX + 3]);
      unsigned int y2 = cvtpk(st[tt][4 * gY + 2], st[tt][4 * gY + 3]);
      plswap(x2, y2);
      union { unsigned int u[4]; bf16x8 b; } cc;
      cc.u[0] = x1; cc.u[1] = x2; cc.u[2] = y1; cc.u[3] = y2;
      pfr[ks] = cc.b;
    }
    // ---- O^T += V^T P (V^T rows read like K rows) ----
    __builtin_amdgcn_s_setprio(1);
    #pragma unroll
    for (int dt = 0; dt < 2; ++dt)
      #pragma unroll
      for (int ks = 0; ks < 4; ++ks) {
        int vrow = dt * 32 + q31;
        bf16x8 vf = *(const bf16x8*)&Vl[cur][vrow * 64 + (((2 * ks + hi) ^ (vrow & 7)) * 8)];
        oa[dt] = __builtin_amdgcn_mfma_f32_32x32x16_bf16(vf, pfr[ks], oa[dt], 0, 0, 0);
      }
    __builtin_amdgcn_s_setprio(0);
    __syncthreads();   // next tile resident; reads of cur done before overwrite
  }
  // ---- epilogue: O[qmy][d], d = 32dt + (r&3) + 8(r>>2) + 4hi ----
  float inv = 1.0f / ls;
  #pragma unroll
  for (int dt = 0; dt < 2; ++dt)
    #pragma unroll
    for (int g = 0; g < 4; ++g) {
      ushort4 o4;
      o4.x = f2bf(oa[dt][4 * g + 0] * inv);
      o4.y = f2bf(oa[dt][4 * g + 1] * inv);
      o4.z = f2bf(oa[dt][4 * g + 2] * inv);
      o4.w = f2bf(oa[dt][4 * g + 3] * inv);
      *(ushort4*)&O[qgrow * 1024 + h * 64 + dt * 32 + 8 * g + 4 * hi] = o4;
    }
}

// ---------------- launch ----------------
extern "C" void kernel_launch(void* const* d_in, const int* in_sizes, int n_in,
                              void* d_out, int out_size, void* d_ws, size_t ws_size,
                              hipStream_t stream) {
  const float* x  = (const float*)d_in[0];
  const float* Wq = (const float*)d_in[1];
  const float* Wk = (const float*)d_in[2];
  const float* Wv = (const float*)d_in[3];
  const float* Wo = (const float*)d_in[4];
  char* ws = (char*)d_ws;
  unsigned short* xb   = (unsigned short*)(ws);                    // 8 MiB (x bf16; later reused as Vt)
  unsigned short* Wb   = (unsigned short*)(ws + (8u << 20));       // 6 MiB
  unsigned short* Wob  = (unsigned short*)(ws + (14u << 20));      // 2 MiB
  unsigned short* QKVb = (unsigned short*)(ws + (16u << 20));      // 24 MiB
  unsigned short* Ob   = (unsigned short*)(ws + (40u << 20));      // 8 MiB
  unsigned short* Vtg  = xb;                                       // reuse: x dead after QKV GEMM

  cvt_k<<<4096, 256, 0, stream>>>(x, xb, 4096 * 1024 / 4);
  cvt_k<<<1024, 256, 0, stream>>>(Wq, Wb, 1024 * 1024 / 4);
  cvt_k<<<1024, 256, 0, stream>>>(Wk, Wb + 1024 * 1024, 1024 * 1024 / 4);
  cvt_k<<<1024, 256, 0, stream>>>(Wv, Wb + 2 * 1024 * 1024, 1024 * 1024 / 4);
  cvt_k<<<1024, 256, 0, stream>>>(Wo, Wob, 1024 * 1024 / 4);

  gemm_bt<0><<<dim3(32, 24), 256, 0, stream>>>(xb, Wb, QKVb, 3072, 1024);
  rope_k<<<(4096 * 512) / 256, 256, 0, stream>>>(QKVb);
  vtr_k<<<dim3(32, 32), 256, 0, stream>>>(QKVb, Vtg);
  attn_k<<<dim3(32, 32), 128, 0, stream>>>(QKVb, Vtg, Ob);
  gemm_bt<1><<<dim3(32, 8), 256, 0, stream>>>(Ob, Wob, d_out, 1024, 1024);
}

// Round 7
// 151.090 us; speedup vs baseline: 1.8733x; 1.0966x over previous
//
#include <hip/hip_runtime.h>

typedef __attribute__((ext_vector_type(8))) short bf16x8;
typedef __attribute__((ext_vector_type(4))) float f32x4;
typedef __attribute__((ext_vector_type(16))) float f32x16;

typedef const __attribute__((address_space(1))) unsigned int gu32;
typedef __attribute__((address_space(3))) unsigned int lu32;

__device__ __forceinline__ void async16(const void* g, void* l) {
  __builtin_amdgcn_global_load_lds((gu32*)g, (lu32*)l, 16, 0, 0);
}

__device__ __forceinline__ unsigned short f2bf(float f) {
  unsigned int u = __float_as_uint(f);
  u += 0x7fffu + ((u >> 16) & 1u);
  return (unsigned short)(u >> 16);
}
__device__ __forceinline__ float b2f(unsigned short s) {
  return __uint_as_float(((unsigned int)s) << 16);
}
__device__ __forceinline__ unsigned int cvtpk(float lo, float hi) {
  unsigned int w;
  asm("v_cvt_pk_bf16_f32 %0, %1, %2" : "=v"(w) : "v"(lo), "v"(hi));
  return w;
}
__device__ __forceinline__ void plswap(unsigned int& x, unsigned int& y) {
  asm("v_permlane32_swap_b32 %0, %1" : "+v"(x), "+v"(y));
}

// ---------------- fp32 -> bf16 conversion ----------------
__global__ __launch_bounds__(256) void cvt_k(const float* __restrict__ in,
                                             unsigned short* __restrict__ out,
                                             int n4) {
  int i = blockIdx.x * 256 + threadIdx.x;
  if (i >= n4) return;
  float4 v = ((const float4*)in)[i];
  ushort4 o;
  o.x = f2bf(v.x); o.y = f2bf(v.y); o.z = f2bf(v.z); o.w = f2bf(v.w);
  ((ushort4*)out)[i] = o;
}

// ---------------- GEMM: C[m][n] = sum_k A[m][k] * B[n][k] ----------------
template <int WRITE_F32>
__global__ __launch_bounds__(256) void gemm_bt(const unsigned short* __restrict__ A,
                                               const unsigned short* __restrict__ B,
                                               void* __restrict__ Cp, int N, int K) {
  __shared__ __align__(16) unsigned short Al[128 * 64];
  __shared__ __align__(16) unsigned short Bl[128 * 64];
  const int t = threadIdx.x;
  const int w = t >> 6, l = t & 63;
  const int wm = w >> 1, wn = w & 1;
  const int lr = l & 15, lg = l >> 4;
  const long bm = (long)blockIdx.x * 128, bn = (long)blockIdx.y * 128;
  const int srow = t >> 3, scol = (t & 7) * 8;
  f32x4 acc[4][4] = {};
  for (int k0 = 0; k0 < K; k0 += 64) {
    __syncthreads();
    #pragma unroll
    for (int r = 0; r < 4; ++r) {
      int row = r * 32 + srow;
      async16(&A[(bm + row) * (long)K + k0 + scol], &Al[row * 64 + scol]);
      async16(&B[(bn + row) * (long)K + k0 + scol], &Bl[row * 64 + scol]);
    }
    __syncthreads();
    #pragma unroll
    for (int ks = 0; ks < 2; ++ks) {
      bf16x8 af[4], bf[4];
      #pragma unroll
      for (int i = 0; i < 4; ++i) {
        af[i] = *(const bf16x8*)&Al[(wm * 64 + i * 16 + lr) * 64 + ks * 32 + lg * 8];
        bf[i] = *(const bf16x8*)&Bl[(wn * 64 + i * 16 + lr) * 64 + ks * 32 + lg * 8];
      }
      #pragma unroll
      for (int i = 0; i < 4; ++i)
        #pragma unroll
        for (int j = 0; j < 4; ++j)
          acc[i][j] = __builtin_amdgcn_mfma_f32_16x16x32_bf16(af[i], bf[j], acc[i][j], 0, 0, 0);
    }
  }
  #pragma unroll
  for (int i = 0; i < 4; ++i)
    #pragma unroll
    for (int j = 0; j < 4; ++j)
      #pragma unroll
      for (int r = 0; r < 4; ++r) {
        long row = bm + wm * 64 + i * 16 + lg * 4 + r;
        long col = bn + wn * 64 + j * 16 + lr;
        float v = acc[i][j][r];
        if (WRITE_F32) ((float*)Cp)[row * N + col] = v;
        else ((unsigned short*)Cp)[row * N + col] = f2bf(v);
      }
}

// ---------------- RoPE in-place on Q and K blocks of QKV ----------------
__global__ __launch_bounds__(256) void rope_k(unsigned short* __restrict__ QKV) {
  int idx = blockIdx.x * 256 + threadIdx.x;
  int row = idx >> 9;
  int rem = idx & 511;
  int h = rem >> 5;
  int i = rem & 31;
  int s = row & 2047;
  float invf = exp2f((float)i * (-13.287712379549449f / 32.0f));
  float ang = (float)s * invf;
  float sn, cs;
  sincosf(ang, &sn, &cs);
  size_t base = (size_t)row * 3072 + h * 64 + 2 * i;
  #pragma unroll
  for (int qk = 0; qk < 2; ++qk) {
    size_t off = base + (size_t)qk * 1024;
    float x1 = b2f(QKV[off]);
    float x2 = b2f(QKV[off + 1]);
    QKV[off]     = f2bf(x1 * cs - x2 * sn);
    QKV[off + 1] = f2bf(x1 * sn + x2 * cs);
  }
}

// ---------------- V transpose: QKV V-part -> Vt[bh][d=64][k=2048] ----------
__global__ __launch_bounds__(256) void vtr_k(const unsigned short* __restrict__ QKV,
                                             unsigned short* __restrict__ Vt) {
  __shared__ unsigned short tl[64][66];
  const int kt = blockIdx.x;            // k-tile 0..31
  const int bh = blockIdx.y;            // 0..31
  const int b = bh >> 4, h = bh & 15;
  const int t = threadIdx.x;
  const int row = t >> 3, c8 = t & 7;
  #pragma unroll
  for (int r = 0; r < 2; ++r) {
    int k = r * 32 + row;
    bf16x8 v = *(const bf16x8*)&QKV[((long)b * 2048 + kt * 64 + k) * 3072 + 2048 + h * 64 + c8 * 8];
    #pragma unroll
    for (int j = 0; j < 8; ++j) tl[c8 * 8 + j][k] = (unsigned short)v[j];
  }
  __syncthreads();
  #pragma unroll
  for (int r = 0; r < 2; ++r) {
    int d = r * 32 + row;
    ushort4 a, bq;
    a.x = tl[d][c8 * 8 + 0]; a.y = tl[d][c8 * 8 + 1];
    a.z = tl[d][c8 * 8 + 2]; a.w = tl[d][c8 * 8 + 3];
    bq.x = tl[d][c8 * 8 + 4]; bq.y = tl[d][c8 * 8 + 5];
    bq.z = tl[d][c8 * 8 + 6]; bq.w = tl[d][c8 * 8 + 7];
    long off = ((long)bh * 64 + d) * 2048 + kt * 64 + c8 * 8;
    *(ushort4*)&Vt[off] = a;
    *(ushort4*)&Vt[off + 4] = bq;
  }
}

// ---------------- causal flash attention ----------------
// 64 q-rows/block, 2 waves, 128 threads. Swapped-QK^T 32x32. K and V^T staged
// row-major via global_load_lds with XOR column swizzle. 3-buffer rotation,
// counted s_waitcnt vmcnt(8): at iter kt we require STAGE(kt) (issued 2 phases
// earlier) landed while STAGE(kt+1)'s 8 loads stay in flight. grid.x = bh so
// all blocks of a head share an XCD (id%8 == bh%8) -> K/V L2-resident.
__global__ __launch_bounds__(128) void attn_k(const unsigned short* __restrict__ QKV,
                                              const unsigned short* __restrict__ VtG,
                                              unsigned short* __restrict__ O) {
  __shared__ __align__(16) unsigned short Kl[3][64 * 64];   // K tile [k][d], swz
  __shared__ __align__(16) unsigned short Vl[3][64 * 64];   // V^T tile [d][k], swz
  const int t = threadIdx.x;
  const int w = t >> 6, l = t & 63;
  const int q31 = l & 31, hi = l >> 5;
  const int bh = blockIdx.x;               // same head -> same XCD
  const int qt = 31 - (int)blockIdx.y;     // LPT: longest first
  const int b = bh >> 4, h = bh & 15;
  const int Qb = qt * 64;
  const long rowb = (long)b * 2048;
  const int L = 3072;
  const int NT = qt + 1;
  const int srow = t >> 3;                 // 0..15
  const int scol = (t & 7) * 8;
  const int scolK = ((t & 7) ^ (srow & 7)) * 8;
  const float cexp = 0.125f * 1.4426950408889634f;

  const int qmy = Qb + 32 * w + q31;
  const long qgrow = rowb + qmy;

  // Q fragments: lane holds Q[qmy][16dk + 8hi + 0..7]
  bf16x8 qf[4];
  #pragma unroll
  for (int dk = 0; dk < 4; ++dk)
    qf[dk] = *(const bf16x8*)&QKV[qgrow * L + h * 64 + dk * 16 + hi * 8];

  float m_ = -1e30f, ls = 0.0f;
  f32x16 oa[2];
  #pragma unroll
  for (int dt = 0; dt < 2; ++dt)
    #pragma unroll
    for (int r = 0; r < 16; ++r) oa[dt][r] = 0.0f;

  auto STAGE = [&](int ts) {   // 8 async16 per thread (4 K + 4 V)
    const int bi = ts % 3;
    const long kb = rowb + (long)ts * 64;
    const long vrowb = (long)bh * 64;
    #pragma unroll
    for (int r = 0; r < 4; ++r) {
      int row = r * 16 + srow;
      async16(&QKV[(kb + row) * L + 1024 + h * 64 + scolK], &Kl[bi][row * 64 + scol]);
      async16(&VtG[(vrowb + row) * 2048 + ts * 64 + scolK], &Vl[bi][row * 64 + scol]);
    }
  };

  STAGE(0);
  if (NT > 1) STAGE(1);

  for (int kt = 0; kt < NT; ++kt) {
    const int cur = kt % 3;
    // wait: STAGE(kt) landed; STAGE(kt+1) (8 newest VMEM ops) may stay in flight
    if (kt < NT - 1) asm volatile("s_waitcnt vmcnt(8)" ::: "memory");
    else             asm volatile("s_waitcnt vmcnt(0)" ::: "memory");
    __builtin_amdgcn_s_barrier();
    __builtin_amdgcn_sched_barrier(0);
    if (kt + 2 < NT) STAGE(kt + 2);

    // ---- S^T = K Q^T ----
    f32x16 st[2];
    #pragma unroll
    for (int kt2 = 0; kt2 < 2; ++kt2)
      #pragma unroll
      for (int r = 0; r < 16; ++r) st[kt2][r] = 0.0f;
    __builtin_amdgcn_s_setprio(1);
    #pragma unroll
    for (int dk = 0; dk < 4; ++dk)
      #pragma unroll
      for (int kt2 = 0; kt2 < 2; ++kt2) {
        int krow = kt2 * 32 + q31;
        bf16x8 kfr = *(const bf16x8*)&Kl[cur][krow * 64 + (((2 * dk + hi) ^ (krow & 7)) * 8)];
        st[kt2] = __builtin_amdgcn_mfma_f32_32x32x16_bf16(kfr, qf[dk], st[kt2], 0, 0, 0);
      }
    __builtin_amdgcn_s_setprio(0);
    // ---- causal mask (diagonal tile only) ----
    if (kt == NT - 1) {
      #pragma unroll
      for (int kt2 = 0; kt2 < 2; ++kt2)
        #pragma unroll
        for (int r = 0; r < 16; ++r) {
          int kg = kt * 64 + kt2 * 32 + (r & 3) + 8 * (r >> 2) + 4 * hi;
          if (kg > qmy) st[kt2][r] = -1e30f;
        }
    }
    // ---- online softmax, tree reductions ----
    float m0[8];
    #pragma unroll
    for (int i = 0; i < 8; ++i)
      m0[i] = fmaxf(fmaxf(st[0][i], st[0][i + 8]), fmaxf(st[1][i], st[1][i + 8]));
    float mt = fmaxf(fmaxf(fmaxf(m0[0], m0[1]), fmaxf(m0[2], m0[3])),
                     fmaxf(fmaxf(m0[4], m0[5]), fmaxf(m0[6], m0[7])));
    mt = fmaxf(mt, __shfl_xor(mt, 32, 64));
    if (__any((mt - m_) * cexp > 8.0f)) {   // defer-max (T13)
      float mn = fmaxf(m_, mt);
      float al = __builtin_amdgcn_exp2f((m_ - mn) * cexp);
      m_ = mn;
      ls *= al;
      #pragma unroll
      for (int dt = 0; dt < 2; ++dt)
        #pragma unroll
        for (int r = 0; r < 16; ++r) oa[dt][r] *= al;
    }
    const float mc = m_ * cexp;
    #pragma unroll
    for (int kt2 = 0; kt2 < 2; ++kt2)
      #pragma unroll
      for (int r = 0; r < 16; ++r)
        st[kt2][r] = __builtin_amdgcn_exp2f(fmaf(st[kt2][r], cexp, -mc));
    float s0[8];
    #pragma unroll
    for (int i = 0; i < 8; ++i)
      s0[i] = (st[0][i] + st[0][i + 8]) + (st[1][i] + st[1][i + 8]);
    float rs = ((s0[0] + s0[1]) + (s0[2] + s0[3])) + ((s0[4] + s0[5]) + (s0[6] + s0[7]));
    rs += __shfl_xor(rs, 32, 64);
    ls += rs;
    // ---- pack P into PV B-frags via cvt_pk + permlane32_swap ----
    bf16x8 pfr[4];
    #pragma unroll
    for (int ks = 0; ks < 4; ++ks) {
      int tt = ks >> 1, gX = 2 * (ks & 1), gY = gX + 1;
      unsigned int x1 = cvtpk(st[tt][4 * gX + 0], st[tt][4 * gX + 1]);
      unsigned int y1 = cvtpk(st[tt][4 * gY + 0], st[tt][4 * gY + 1]);
      plswap(x1, y1);
      unsigned int x2 = cvtpk(st[tt][4 * gX + 2], st[tt][4 * gX + 3]);
      unsigned int y2 = cvtpk(st[tt][4 * gY + 2], st[tt][4 * gY + 3]);
      plswap(x2, y2);
      union { unsigned int u[4]; bf16x8 b; } cc;
      cc.u[0] = x1; cc.u[1] = x2; cc.u[2] = y1; cc.u[3] = y2;
      pfr[ks] = cc.b;
    }
    // ---- O^T += V^T P (V^T rows read like K rows) ----
    __builtin_amdgcn_s_setprio(1);
    #pragma unroll
    for (int dt = 0; dt < 2; ++dt)
      #pragma unroll
      for (int ks = 0; ks < 4; ++ks) {
        int vrow = dt * 32 + q31;
        bf16x8 vf = *(const bf16x8*)&Vl[cur][vrow * 64 + (((2 * ks + hi) ^ (vrow & 7)) * 8)];
        oa[dt] = __builtin_amdgcn_mfma_f32_32x32x16_bf16(vf, pfr[ks], oa[dt], 0, 0, 0);
      }
    __builtin_amdgcn_s_setprio(0);
  }
  // ---- epilogue: O[qmy][d], d = 32dt + (r&3) + 8(r>>2) + 4hi ----
  float inv = 1.0f / ls;
  #pragma unroll
  for (int dt = 0; dt < 2; ++dt)
    #pragma unroll
    for (int g = 0; g < 4; ++g) {
      ushort4 o4;
      o4.x = f2bf(oa[dt][4 * g + 0] * inv);
      o4.y = f2bf(oa[dt][4 * g + 1] * inv);
      o4.z = f2bf(oa[dt][4 * g + 2] * inv);
      o4.w = f2bf(oa[dt][4 * g + 3] * inv);
      *(ushort4*)&O[qgrow * 1024 + h * 64 + dt * 32 + 8 * g + 4 * hi] = o4;
    }
}

// ---------------- launch ----------------
extern "C" void kernel_launch(void* const* d_in, const int* in_sizes, int n_in,
                              void* d_out, int out_size, void* d_ws, size_t ws_size,
                              hipStream_t stream) {
  const float* x  = (const float*)d_in[0];
  const float* Wq = (const float*)d_in[1];
  const float* Wk = (const float*)d_in[2];
  const float* Wv = (const float*)d_in[3];
  const float* Wo = (const float*)d_in[4];
  char* ws = (char*)d_ws;
  unsigned short* xb   = (unsigned short*)(ws);                    // 8 MiB (x bf16; later reused as Vt)
  unsigned short* Wb   = (unsigned short*)(ws + (8u << 20));       // 6 MiB
  unsigned short* Wob  = (unsigned short*)(ws + (14u << 20));      // 2 MiB
  unsigned short* QKVb = (unsigned short*)(ws + (16u << 20));      // 24 MiB
  unsigned short* Ob   = (unsigned short*)(ws + (40u << 20));      // 8 MiB
  unsigned short* Vtg  = xb;                                       // reuse: x dead after QKV GEMM

  cvt_k<<<4096, 256, 0, stream>>>(x, xb, 4096 * 1024 / 4);
  cvt_k<<<1024, 256, 0, stream>>>(Wq, Wb, 1024 * 1024 / 4);
  cvt_k<<<1024, 256, 0, stream>>>(Wk, Wb + 1024 * 1024, 1024 * 1024 / 4);
  cvt_k<<<1024, 256, 0, stream>>>(Wv, Wb + 2 * 1024 * 1024, 1024 * 1024 / 4);
  cvt_k<<<1024, 256, 0, stream>>>(Wo, Wob, 1024 * 1024 / 4);

  gemm_bt<0><<<dim3(32, 24), 256, 0, stream>>>(xb, Wb, QKVb, 3072, 1024);
  rope_k<<<(4096 * 512) / 256, 256, 0, stream>>>(QKVb);
  vtr_k<<<dim3(32, 32), 256, 0, stream>>>(QKVb, Vtg);
  attn_k<<<dim3(32, 32), 128, 0, stream>>>(QKVb, Vtg, Ob);
  gemm_bt<1><<<dim3(32, 8), 256, 0, stream>>>(Ob, Wob, d_out, 1024, 1024);
}

// Round 8
// 137.385 us; speedup vs baseline: 2.0602x; 1.0998x over previous
//
#include <hip/hip_runtime.h>

typedef __attribute__((ext_vector_type(8))) short bf16x8;
typedef __attribute__((ext_vector_type(4))) float f32x4;
typedef __attribute__((ext_vector_type(16))) float f32x16;

typedef const __attribute__((address_space(1))) unsigned int gu32;
typedef __attribute__((address_space(3))) unsigned int lu32;

__device__ __forceinline__ void async16(const void* g, void* l) {
  __builtin_amdgcn_global_load_lds((gu32*)g, (lu32*)l, 16, 0, 0);
}

__device__ __forceinline__ unsigned short f2bf(float f) {
  unsigned int u = __float_as_uint(f);
  u += 0x7fffu + ((u >> 16) & 1u);
  return (unsigned short)(u >> 16);
}
__device__ __forceinline__ float b2f(unsigned short s) {
  return __uint_as_float(((unsigned int)s) << 16);
}
__device__ __forceinline__ unsigned int cvtpk(float lo, float hi) {
  unsigned int w;
  asm("v_cvt_pk_bf16_f32 %0, %1, %2" : "=v"(w) : "v"(lo), "v"(hi));
  return w;
}
__device__ __forceinline__ void plswap(unsigned int& x, unsigned int& y) {
  asm("v_permlane32_swap_b32 %0, %1" : "+v"(x), "+v"(y));
}

// ---------------- fp32 -> bf16 conversion ----------------
__global__ __launch_bounds__(256) void cvt_k(const float* __restrict__ in,
                                             unsigned short* __restrict__ out,
                                             int n4) {
  int i = blockIdx.x * 256 + threadIdx.x;
  if (i >= n4) return;
  float4 v = ((const float4*)in)[i];
  ushort4 o;
  o.x = f2bf(v.x); o.y = f2bf(v.y); o.z = f2bf(v.z); o.w = f2bf(v.w);
  ((ushort4*)out)[i] = o;
}

// ---------------- GEMM: C[m][n] = sum_k A[m][k] * B[n][k] ----------------
// 128x128 tile, BK=64, 4 waves. Depth-1 pipelined K-loop (one barrier/iter,
// vmcnt(0) waits on the tile issued a full iteration earlier). A/B LDS tiles
// XOR-column-swizzled: linear global_load_lds dest + pre-swizzled global
// source; frag reads use slot (ks*4+lg)^(lr&7) -> all 8 chunk-slots covered.
template <int WRITE_F32>
__global__ __launch_bounds__(256) void gemm_bt(const unsigned short* __restrict__ A,
                                               const unsigned short* __restrict__ B,
                                               void* __restrict__ Cp, int N, int K) {
  __shared__ __align__(16) unsigned short Al[2][128 * 64];
  __shared__ __align__(16) unsigned short Bl[2][128 * 64];
  const int t = threadIdx.x;
  const int w = t >> 6, l = t & 63;
  const int wm = w >> 1, wn = w & 1;
  const int lr = l & 15, lg = l >> 4;
  const long bm = (long)blockIdx.x * 128, bn = (long)blockIdx.y * 128;
  const int srow = t >> 3;                       // 0..31
  const int scol = (t & 7) * 8;                  // linear LDS col
  const int scolS = ((t & 7) ^ (srow & 7)) * 8;  // swizzled global col
  const int KT = K >> 6;
  f32x4 acc[4][4] = {};

  auto STAGE = [&](int ts) {   // 8 async16 per thread (4 A + 4 B rows)
    const int bi = ts & 1;
    const int k0 = ts * 64;
    #pragma unroll
    for (int r = 0; r < 4; ++r) {
      int row = r * 32 + srow;
      async16(&A[(bm + row) * (long)K + k0 + scolS], &Al[bi][row * 64 + scol]);
      async16(&B[(bn + row) * (long)K + k0 + scolS], &Bl[bi][row * 64 + scol]);
    }
  };

  STAGE(0);
  for (int kt = 0; kt < KT; ++kt) {
    const int cur = kt & 1;
    asm volatile("s_waitcnt vmcnt(0)" ::: "memory");  // tile kt landed (wave-local)
    __builtin_amdgcn_s_barrier();                     // all waves' tile kt landed;
    __builtin_amdgcn_sched_barrier(0);                // readers of buf cur^1 done
    if (kt + 1 < KT) STAGE(kt + 1);                   // prefetch into buf cur^1
    #pragma unroll
    for (int ks = 0; ks < 2; ++ks) {
      const int slot = ((ks * 4 + lg) ^ (lr & 7)) * 8;
      bf16x8 af[4], bf[4];
      #pragma unroll
      for (int i = 0; i < 4; ++i) {
        af[i] = *(const bf16x8*)&Al[cur][(wm * 64 + i * 16 + lr) * 64 + slot];
        bf[i] = *(const bf16x8*)&Bl[cur][(wn * 64 + i * 16 + lr) * 64 + slot];
      }
      #pragma unroll
      for (int i = 0; i < 4; ++i)
        #pragma unroll
        for (int j = 0; j < 4; ++j)
          acc[i][j] = __builtin_amdgcn_mfma_f32_16x16x32_bf16(af[i], bf[j], acc[i][j], 0, 0, 0);
    }
  }
  #pragma unroll
  for (int i = 0; i < 4; ++i)
    #pragma unroll
    for (int j = 0; j < 4; ++j)
      #pragma unroll
      for (int r = 0; r < 4; ++r) {
        long row = bm + wm * 64 + i * 16 + lg * 4 + r;
        long col = bn + wn * 64 + j * 16 + lr;
        float v = acc[i][j][r];
        if (WRITE_F32) ((float*)Cp)[row * N + col] = v;
        else ((unsigned short*)Cp)[row * N + col] = f2bf(v);
      }
}

// ---------------- RoPE in-place on Q and K blocks of QKV ----------------
__global__ __launch_bounds__(256) void rope_k(unsigned short* __restrict__ QKV) {
  int idx = blockIdx.x * 256 + threadIdx.x;
  int row = idx >> 9;
  int rem = idx & 511;
  int h = rem >> 5;
  int i = rem & 31;
  int s = row & 2047;
  float invf = exp2f((float)i * (-13.287712379549449f / 32.0f));
  float ang = (float)s * invf;
  float sn, cs;
  sincosf(ang, &sn, &cs);
  size_t base = (size_t)row * 3072 + h * 64 + 2 * i;
  #pragma unroll
  for (int qk = 0; qk < 2; ++qk) {
    size_t off = base + (size_t)qk * 1024;
    float x1 = b2f(QKV[off]);
    float x2 = b2f(QKV[off + 1]);
    QKV[off]     = f2bf(x1 * cs - x2 * sn);
    QKV[off + 1] = f2bf(x1 * sn + x2 * cs);
  }
}

// ---------------- V transpose: QKV V-part -> Vt[bh][d=64][k=2048] ----------
__global__ __launch_bounds__(256) void vtr_k(const unsigned short* __restrict__ QKV,
                                             unsigned short* __restrict__ Vt) {
  __shared__ unsigned short tl[64][66];
  const int kt = blockIdx.x;            // k-tile 0..31
  const int bh = blockIdx.y;            // 0..31
  const int b = bh >> 4, h = bh & 15;
  const int t = threadIdx.x;
  const int row = t >> 3, c8 = t & 7;
  #pragma unroll
  for (int r = 0; r < 2; ++r) {
    int k = r * 32 + row;
    bf16x8 v = *(const bf16x8*)&QKV[((long)b * 2048 + kt * 64 + k) * 3072 + 2048 + h * 64 + c8 * 8];
    #pragma unroll
    for (int j = 0; j < 8; ++j) tl[c8 * 8 + j][k] = (unsigned short)v[j];
  }
  __syncthreads();
  #pragma unroll
  for (int r = 0; r < 2; ++r) {
    int d = r * 32 + row;
    ushort4 a, bq;
    a.x = tl[d][c8 * 8 + 0]; a.y = tl[d][c8 * 8 + 1];
    a.z = tl[d][c8 * 8 + 2]; a.w = tl[d][c8 * 8 + 3];
    bq.x = tl[d][c8 * 8 + 4]; bq.y = tl[d][c8 * 8 + 5];
    bq.z = tl[d][c8 * 8 + 6]; bq.w = tl[d][c8 * 8 + 7];
    long off = ((long)bh * 64 + d) * 2048 + kt * 64 + c8 * 8;
    *(ushort4*)&Vt[off] = a;
    *(ushort4*)&Vt[off + 4] = bq;
  }
}

// ---------------- causal flash attention (R7, unchanged) ----------------
__global__ __launch_bounds__(128) void attn_k(const unsigned short* __restrict__ QKV,
                                              const unsigned short* __restrict__ VtG,
                                              unsigned short* __restrict__ O) {
  __shared__ __align__(16) unsigned short Kl[3][64 * 64];   // K tile [k][d], swz
  __shared__ __align__(16) unsigned short Vl[3][64 * 64];   // V^T tile [d][k], swz
  const int t = threadIdx.x;
  const int w = t >> 6, l = t & 63;
  const int q31 = l & 31, hi = l >> 5;
  const int bh = blockIdx.x;               // same head -> same XCD
  const int qt = 31 - (int)blockIdx.y;     // LPT: longest first
  const int b = bh >> 4, h = bh & 15;
  const int Qb = qt * 64;
  const long rowb = (long)b * 2048;
  const int L = 3072;
  const int NT = qt + 1;
  const int srow = t >> 3;                 // 0..15
  const int scol = (t & 7) * 8;
  const int scolK = ((t & 7) ^ (srow & 7)) * 8;
  const float cexp = 0.125f * 1.4426950408889634f;

  const int qmy = Qb + 32 * w + q31;
  const long qgrow = rowb + qmy;

  bf16x8 qf[4];
  #pragma unroll
  for (int dk = 0; dk < 4; ++dk)
    qf[dk] = *(const bf16x8*)&QKV[qgrow * L + h * 64 + dk * 16 + hi * 8];

  float m_ = -1e30f, ls = 0.0f;
  f32x16 oa[2];
  #pragma unroll
  for (int dt = 0; dt < 2; ++dt)
    #pragma unroll
    for (int r = 0; r < 16; ++r) oa[dt][r] = 0.0f;

  auto STAGE = [&](int ts) {   // 8 async16 per thread (4 K + 4 V)
    const int bi = ts % 3;
    const long kb = rowb + (long)ts * 64;
    const long vrowb = (long)bh * 64;
    #pragma unroll
    for (int r = 0; r < 4; ++r) {
      int row = r * 16 + srow;
      async16(&QKV[(kb + row) * L + 1024 + h * 64 + scolK], &Kl[bi][row * 64 + scol]);
      async16(&VtG[(vrowb + row) * 2048 + ts * 64 + scolK], &Vl[bi][row * 64 + scol]);
    }
  };

  STAGE(0);
  if (NT > 1) STAGE(1);

  for (int kt = 0; kt < NT; ++kt) {
    const int cur = kt % 3;
    if (kt < NT - 1) asm volatile("s_waitcnt vmcnt(8)" ::: "memory");
    else             asm volatile("s_waitcnt vmcnt(0)" ::: "memory");
    __builtin_amdgcn_s_barrier();
    __builtin_amdgcn_sched_barrier(0);
    if (kt + 2 < NT) STAGE(kt + 2);

    // ---- S^T = K Q^T ----
    f32x16 st[2];
    #pragma unroll
    for (int kt2 = 0; kt2 < 2; ++kt2)
      #pragma unroll
      for (int r = 0; r < 16; ++r) st[kt2][r] = 0.0f;
    __builtin_amdgcn_s_setprio(1);
    #pragma unroll
    for (int dk = 0; dk < 4; ++dk)
      #pragma unroll
      for (int kt2 = 0; kt2 < 2; ++kt2) {
        int krow = kt2 * 32 + q31;
        bf16x8 kfr = *(const bf16x8*)&Kl[cur][krow * 64 + (((2 * dk + hi) ^ (krow & 7)) * 8)];
        st[kt2] = __builtin_amdgcn_mfma_f32_32x32x16_bf16(kfr, qf[dk], st[kt2], 0, 0, 0);
      }
    __builtin_amdgcn_s_setprio(0);
    if (kt == NT - 1) {
      #pragma unroll
      for (int kt2 = 0; kt2 < 2; ++kt2)
        #pragma unroll
        for (int r = 0; r < 16; ++r) {
          int kg = kt * 64 + kt2 * 32 + (r & 3) + 8 * (r >> 2) + 4 * hi;
          if (kg > qmy) st[kt2][r] = -1e30f;
        }
    }
    // ---- online softmax, tree reductions ----
    float m0[8];
    #pragma unroll
    for (int i = 0; i < 8; ++i)
      m0[i] = fmaxf(fmaxf(st[0][i], st[0][i + 8]), fmaxf(st[1][i], st[1][i + 8]));
    float mt = fmaxf(fmaxf(fmaxf(m0[0], m0[1]), fmaxf(m0[2], m0[3])),
                     fmaxf(fmaxf(m0[4], m0[5]), fmaxf(m0[6], m0[7])));
    mt = fmaxf(mt, __shfl_xor(mt, 32, 64));
    if (__any((mt - m_) * cexp > 8.0f)) {   // defer-max (T13)
      float mn = fmaxf(m_, mt);
      float al = __builtin_amdgcn_exp2f((m_ - mn) * cexp);
      m_ = mn;
      ls *= al;
      #pragma unroll
      for (int dt = 0; dt < 2; ++dt)
        #pragma unroll
        for (int r = 0; r < 16; ++r) oa[dt][r] *= al;
    }
    const float mc = m_ * cexp;
    #pragma unroll
    for (int kt2 = 0; kt2 < 2; ++kt2)
      #pragma unroll
      for (int r = 0; r < 16; ++r)
        st[kt2][r] = __builtin_amdgcn_exp2f(fmaf(st[kt2][r], cexp, -mc));
    float s0[8];
    #pragma unroll
    for (int i = 0; i < 8; ++i)
      s0[i] = (st[0][i] + st[0][i + 8]) + (st[1][i] + st[1][i + 8]);
    float rs = ((s0[0] + s0[1]) + (s0[2] + s0[3])) + ((s0[4] + s0[5]) + (s0[6] + s0[7]));
    rs += __shfl_xor(rs, 32, 64);
    ls += rs;
    // ---- pack P into PV B-frags via cvt_pk + permlane32_swap ----
    bf16x8 pfr[4];
    #pragma unroll
    for (int ks = 0; ks < 4; ++ks) {
      int tt = ks >> 1, gX = 2 * (ks & 1), gY = gX + 1;
      unsigned int x1 = cvtpk(st[tt][4 * gX + 0], st[tt][4 * gX + 1]);
      unsigned int y1 = cvtpk(st[tt][4 * gY + 0], st[tt][4 * gY + 1]);
      plswap(x1, y1);
      unsigned int x2 = cvtpk(st[tt][4 * gX + 2], st[tt][4 * gX + 3]);
      unsigned int y2 = cvtpk(st[tt][4 * gY + 2], st[tt][4 * gY + 3]);
      plswap(x2, y2);
      union { unsigned int u[4]; bf16x8 b; } cc;
      cc.u[0] = x1; cc.u[1] = x2; cc.u[2] = y1; cc.u[3] = y2;
      pfr[ks] = cc.b;
    }
    // ---- O^T += V^T P ----
    __builtin_amdgcn_s_setprio(1);
    #pragma unroll
    for (int dt = 0; dt < 2; ++dt)
      #pragma unroll
      for (int ks = 0; ks < 4; ++ks) {
        int vrow = dt * 32 + q31;
        bf16x8 vf = *(const bf16x8*)&Vl[cur][vrow * 64 + (((2 * ks + hi) ^ (vrow & 7)) * 8)];
        oa[dt] = __builtin_amdgcn_mfma_f32_32x32x16_bf16(vf, pfr[ks], oa[dt], 0, 0, 0);
      }
    __builtin_amdgcn_s_setprio(0);
  }
  // ---- epilogue ----
  float inv = 1.0f / ls;
  #pragma unroll
  for (int dt = 0; dt < 2; ++dt)
    #pragma unroll
    for (int g = 0; g < 4; ++g) {
      ushort4 o4;
      o4.x = f2bf(oa[dt][4 * g + 0] * inv);
      o4.y = f2bf(oa[dt][4 * g + 1] * inv);
      o4.z = f2bf(oa[dt][4 * g + 2] * inv);
      o4.w = f2bf(oa[dt][4 * g + 3] * inv);
      *(ushort4*)&O[qgrow * 1024 + h * 64 + dt * 32 + 8 * g + 4 * hi] = o4;
    }
}

// ---------------- launch ----------------
extern "C" void kernel_launch(void* const* d_in, const int* in_sizes, int n_in,
                              void* d_out, int out_size, void* d_ws, size_t ws_size,
                              hipStream_t stream) {
  const float* x  = (const float*)d_in[0];
  const float* Wq = (const float*)d_in[1];
  const float* Wk = (const float*)d_in[2];
  const float* Wv = (const float*)d_in[3];
  const float* Wo = (const float*)d_in[4];
  char* ws = (char*)d_ws;
  unsigned short* xb   = (unsigned short*)(ws);                    // 8 MiB (x bf16; later reused as Vt)
  unsigned short* Wb   = (unsigned short*)(ws + (8u << 20));       // 6 MiB
  unsigned short* Wob  = (unsigned short*)(ws + (14u << 20));      // 2 MiB
  unsigned short* QKVb = (unsigned short*)(ws + (16u << 20));      // 24 MiB
  unsigned short* Ob   = (unsigned short*)(ws + (40u << 20));      // 8 MiB
  unsigned short* Vtg  = xb;                                       // reuse: x dead after QKV GEMM

  cvt_k<<<4096, 256, 0, stream>>>(x, xb, 4096 * 1024 / 4);
  cvt_k<<<1024, 256, 0, stream>>>(Wq, Wb, 1024 * 1024 / 4);
  cvt_k<<<1024, 256, 0, stream>>>(Wk, Wb + 1024 * 1024, 1024 * 1024 / 4);
  cvt_k<<<1024, 256, 0, stream>>>(Wv, Wb + 2 * 1024 * 1024, 1024 * 1024 / 4);
  cvt_k<<<1024, 256, 0, stream>>>(Wo, Wob, 1024 * 1024 / 4);

  gemm_bt<0><<<dim3(32, 24), 256, 0, stream>>>(xb, Wb, QKVb, 3072, 1024);
  rope_k<<<(4096 * 512) / 256, 256, 0, stream>>>(QKVb);
  vtr_k<<<dim3(32, 32), 256, 0, stream>>>(QKVb, Vtg);
  attn_k<<<dim3(32, 32), 128, 0, stream>>>(QKVb, Vtg, Ob);
  gemm_bt<1><<<dim3(32, 8), 256, 0, stream>>>(Ob, Wob, d_out, 1024, 1024);
}

// Round 10
// 133.682 us; speedup vs baseline: 2.1172x; 1.0277x over previous
//
#include <hip/hip_runtime.h>

typedef __attribute__((ext_vector_type(8))) short bf16x8;
typedef __attribute__((ext_vector_type(4))) float f32x4;
typedef __attribute__((ext_vector_type(16))) float f32x16;

typedef const __attribute__((address_space(1))) unsigned int gu32;
typedef __attribute__((address_space(3))) unsigned int lu32;

__device__ __forceinline__ void async16(const void* g, void* l) {
  __builtin_amdgcn_global_load_lds((gu32*)g, (lu32*)l, 16, 0, 0);
}

__device__ __forceinline__ unsigned short f2bf(float f) {
  unsigned int u = __float_as_uint(f);
  u += 0x7fffu + ((u >> 16) & 1u);
  return (unsigned short)(u >> 16);
}
__device__ __forceinline__ float b2f(unsigned short s) {
  return __uint_as_float(((unsigned int)s) << 16);
}
__device__ __forceinline__ unsigned int cvtpk(float lo, float hi) {
  unsigned int w;
  asm("v_cvt_pk_bf16_f32 %0, %1, %2" : "=v"(w) : "v"(lo), "v"(hi));
  return w;
}
__device__ __forceinline__ void plswap(unsigned int& x, unsigned int& y) {
  asm("v_permlane32_swap_b32 %0, %1" : "+v"(x), "+v"(y));
}

// ---------------- fp32 -> bf16 conversion ----------------
__global__ __launch_bounds__(256) void cvt_k(const float* __restrict__ in,
                                             unsigned short* __restrict__ out,
                                             int n4) {
  int i = blockIdx.x * 256 + threadIdx.x;
  if (i >= n4) return;
  float4 v = ((const float4*)in)[i];
  ushort4 o;
  o.x = f2bf(v.x); o.y = f2bf(v.y); o.z = f2bf(v.z); o.w = f2bf(v.w);
  ((ushort4*)out)[i] = o;
}

// ---------------- GEMM: C[m][n] = sum_k A[m][k] * B[n][k] ----------------
// 128x128 tile, BK=32 double-buffered (32 KB LDS). Depth-1 pipeline:
// vmcnt(0) -> barrier -> STAGE(kt+1) -> 16 MFMA. Staging is lane-linear
// (row = t>>2, chunk = t&3 -> LDS byte = w*1024 + 16*lane per call), which
// the global_load_lds DMA requires. At 64B row stride the b128 frag reads
// tile the 128B LDS line uniformly (8 lanes/16B slot) -> no swizzle needed.
template <int WRITE_F32>
__global__ __launch_bounds__(256) void gemm_bt(const unsigned short* __restrict__ A,
                                               const unsigned short* __restrict__ B,
                                               void* __restrict__ Cp, int N, int K) {
  __shared__ __align__(16) unsigned short Al[2][128 * 32];
  __shared__ __align__(16) unsigned short Bl[2][128 * 32];
  const int t = threadIdx.x;
  const int w = t >> 6, l = t & 63;
  const int wm = w >> 1, wn = w & 1;
  const int lr = l & 15, lg = l >> 4;
  const long bm = (long)blockIdx.x * 128, bn = (long)blockIdx.y * 128;
  const int srow = t >> 2;                 // 0..63 (4 threads per row)
  const int c8 = t & 3;                    // 16B chunk within the 32-elem row
  const int KT = K >> 5;
  f32x4 acc[4][4] = {};

  auto STAGE = [&](int ts) {   // 4 async16 per thread (2 A + 2 B)
    const int bi = ts & 1;
    const int k0 = ts * 32;
    #pragma unroll
    for (int r = 0; r < 2; ++r) {
      int row = r * 64 + srow;
      async16(&A[(bm + row) * (long)K + k0 + c8 * 8], &Al[bi][row * 32 + c8 * 8]);
      async16(&B[(bn + row) * (long)K + k0 + c8 * 8], &Bl[bi][row * 32 + c8 * 8]);
    }
  };

  STAGE(0);
  for (int kt = 0; kt < KT; ++kt) {
    const int cur = kt & 1;
    asm volatile("s_waitcnt vmcnt(0)" ::: "memory");  // tile kt landed
    __builtin_amdgcn_s_barrier();                     // all waves; prev readers done
    __builtin_amdgcn_sched_barrier(0);
    if (kt + 1 < KT) STAGE(kt + 1);                   // prefetch into other buffer
    bf16x8 af[4], bf[4];
    #pragma unroll
    for (int i = 0; i < 4; ++i) {
      af[i] = *(const bf16x8*)&Al[cur][(wm * 64 + i * 16 + lr) * 32 + lg * 8];
      bf[i] = *(const bf16x8*)&Bl[cur][(wn * 64 + i * 16 + lr) * 32 + lg * 8];
    }
    #pragma unroll
    for (int i = 0; i < 4; ++i)
      #pragma unroll
      for (int j = 0; j < 4; ++j)
        acc[i][j] = __builtin_amdgcn_mfma_f32_16x16x32_bf16(af[i], bf[j], acc[i][j], 0, 0, 0);
  }
  #pragma unroll
  for (int i = 0; i < 4; ++i)
    #pragma unroll
    for (int j = 0; j < 4; ++j)
      #pragma unroll
      for (int r = 0; r < 4; ++r) {
        long row = bm + wm * 64 + i * 16 + lg * 4 + r;
        long col = bn + wn * 64 + j * 16 + lr;
        float v = acc[i][j][r];
        if (WRITE_F32) ((float*)Cp)[row * N + col] = v;
        else ((unsigned short*)Cp)[row * N + col] = f2bf(v);
      }
}

// ---------------- RoPE in-place, table-per-row ----------------
__global__ __launch_bounds__(256) void rope_k(unsigned short* __restrict__ QKV) {
  __shared__ float csl[32], snl[32];
  const int row = blockIdx.x;
  const int s = row & 2047;
  const int t = threadIdx.x;
  if (t < 32) {
    float invf = exp2f((float)t * (-13.287712379549449f / 32.0f));
    float sn, cs;
    sincosf((float)s * invf, &sn, &cs);
    csl[t] = cs; snl[t] = sn;
  }
  __syncthreads();
  const int col0 = (t < 128) ? t * 8 : 1024 + (t - 128) * 8;
  const int i0 = (t & 7) * 4;
  unsigned short* p = &QKV[(size_t)row * 3072 + col0];
  bf16x8 v = *(const bf16x8*)p;
  bf16x8 o;
  #pragma unroll
  for (int j = 0; j < 4; ++j) {
    float x1 = b2f((unsigned short)v[2 * j]);
    float x2 = b2f((unsigned short)v[2 * j + 1]);
    float cs = csl[i0 + j], sn = snl[i0 + j];
    o[2 * j]     = (short)f2bf(x1 * cs - x2 * sn);
    o[2 * j + 1] = (short)f2bf(x1 * sn + x2 * cs);
  }
  *(bf16x8*)p = o;
}

// ---------------- V transpose: QKV V-part -> Vt[bh][d=64][k=2048] ----------
__global__ __launch_bounds__(256) void vtr_k(const unsigned short* __restrict__ QKV,
                                             unsigned short* __restrict__ Vt) {
  __shared__ unsigned short tl[64][66];
  const int kt = blockIdx.x;            // k-tile 0..31
  const int bh = blockIdx.y;            // 0..31
  const int b = bh >> 4, h = bh & 15;
  const int t = threadIdx.x;
  const int row = t >> 3, c8 = t & 7;
  #pragma unroll
  for (int r = 0; r < 2; ++r) {
    int k = r * 32 + row;
    bf16x8 v = *(const bf16x8*)&QKV[((long)b * 2048 + kt * 64 + k) * 3072 + 2048 + h * 64 + c8 * 8];
    #pragma unroll
    for (int j = 0; j < 8; ++j) tl[c8 * 8 + j][k] = (unsigned short)v[j];
  }
  __syncthreads();
  #pragma unroll
  for (int r = 0; r < 2; ++r) {
    int d = r * 32 + row;
    ushort4 a, bq;
    a.x = tl[d][c8 * 8 + 0]; a.y = tl[d][c8 * 8 + 1];
    a.z = tl[d][c8 * 8 + 2]; a.w = tl[d][c8 * 8 + 3];
    bq.x = tl[d][c8 * 8 + 4]; bq.y = tl[d][c8 * 8 + 5];
    bq.z = tl[d][c8 * 8 + 6]; bq.w = tl[d][c8 * 8 + 7];
    long off = ((long)bh * 64 + d) * 2048 + kt * 64 + c8 * 8;
    *(ushort4*)&Vt[off] = a;
    *(ushort4*)&Vt[off + 4] = bq;
  }
}

// ---------------- causal flash attention (R9 structure) ----------------
// 64 q-rows/block, 2 waves, 128 threads. Swapped-QK^T 32x32. K/V^T staged via
// global_load_lds + XOR swizzle. 2-buffer depth-1 pipeline (32 KB LDS).
// Softmax: per-lane online state; cross-half shfl only on rescale; ls
// combined once in epilogue. XCD clustering via grid.x = bh.
__global__ __launch_bounds__(128) void attn_k(const unsigned short* __restrict__ QKV,
                                              const unsigned short* __restrict__ VtG,
                                              unsigned short* __restrict__ O) {
  __shared__ __align__(16) unsigned short Kl[2][64 * 64];   // K tile [k][d], swz
  __shared__ __align__(16) unsigned short Vl[2][64 * 64];   // V^T tile [d][k], swz
  const int t = threadIdx.x;
  const int w = t >> 6, l = t & 63;
  const int q31 = l & 31, hi = l >> 5;
  const int bh = blockIdx.x;               // same head -> same XCD
  const int qt = 31 - (int)blockIdx.y;     // LPT: longest first
  const int b = bh >> 4, h = bh & 15;
  const int Qb = qt * 64;
  const long rowb = (long)b * 2048;
  const int L = 3072;
  const int NT = qt + 1;
  const int srow = t >> 3;                 // 0..15
  const int scol = (t & 7) * 8;
  const int scolK = ((t & 7) ^ (srow & 7)) * 8;
  const float cexp = 0.125f * 1.4426950408889634f;

  const int qmy = Qb + 32 * w + q31;
  const long qgrow = rowb + qmy;

  bf16x8 qf[4];
  #pragma unroll
  for (int dk = 0; dk < 4; ++dk)
    qf[dk] = *(const bf16x8*)&QKV[qgrow * L + h * 64 + dk * 16 + hi * 8];

  float m_ = -1e30f, ls = 0.0f;            // ls: per-lane partial (own 32 cols)
  f32x16 oa[2];
  #pragma unroll
  for (int dt = 0; dt < 2; ++dt)
    #pragma unroll
    for (int r = 0; r < 16; ++r) oa[dt][r] = 0.0f;

  auto STAGE = [&](int ts) {   // 8 async16 per thread (4 K + 4 V)
    const int bi = ts & 1;
    const long kb = rowb + (long)ts * 64;
    const long vrowb = (long)bh * 64;
    #pragma unroll
    for (int r = 0; r < 4; ++r) {
      int row = r * 16 + srow;
      async16(&QKV[(kb + row) * L + 1024 + h * 64 + scolK], &Kl[bi][row * 64 + scol]);
      async16(&VtG[(vrowb + row) * 2048 + ts * 64 + scolK], &Vl[bi][row * 64 + scol]);
    }
  };

  STAGE(0);

  for (int kt = 0; kt < NT; ++kt) {
    const int cur = kt & 1;
    asm volatile("s_waitcnt vmcnt(0)" ::: "memory");   // tile kt landed
    __builtin_amdgcn_s_barrier();                      // prev readers done too
    __builtin_amdgcn_sched_barrier(0);
    if (kt + 1 < NT) STAGE(kt + 1);

    // ---- S^T = K Q^T ----
    f32x16 st[2];
    #pragma unroll
    for (int kt2 = 0; kt2 < 2; ++kt2)
      #pragma unroll
      for (int r = 0; r < 16; ++r) st[kt2][r] = 0.0f;
    __builtin_amdgcn_s_setprio(1);
    #pragma unroll
    for (int dk = 0; dk < 4; ++dk)
      #pragma unroll
      for (int kt2 = 0; kt2 < 2; ++kt2) {
        int krow = kt2 * 32 + q31;
        bf16x8 kfr = *(const bf16x8*)&Kl[cur][krow * 64 + (((2 * dk + hi) ^ (krow & 7)) * 8)];
        st[kt2] = __builtin_amdgcn_mfma_f32_32x32x16_bf16(kfr, qf[dk], st[kt2], 0, 0, 0);
      }
    __builtin_amdgcn_s_setprio(0);
    if (kt == NT - 1) {
      #pragma unroll
      for (int kt2 = 0; kt2 < 2; ++kt2)
        #pragma unroll
        for (int r = 0; r < 16; ++r) {
          int kg = kt * 64 + kt2 * 32 + (r & 3) + 8 * (r >> 2) + 4 * hi;
          if (kg > qmy) st[kt2][r] = -1e30f;
        }
    }
    // ---- online softmax: per-lane max; shfl only when rescaling ----
    float m0[8];
    #pragma unroll
    for (int i = 0; i < 8; ++i)
      m0[i] = fmaxf(fmaxf(st[0][i], st[0][i + 8]), fmaxf(st[1][i], st[1][i + 8]));
    float mt = fmaxf(fmaxf(fmaxf(m0[0], m0[1]), fmaxf(m0[2], m0[3])),
                     fmaxf(fmaxf(m0[4], m0[5]), fmaxf(m0[6], m0[7])));
    if (__any((mt - m_) * cexp > 8.0f)) {   // defer-max (T13)
      float mg = fmaxf(mt, __shfl_xor(mt, 32, 64));   // row max (pair-synced)
      float mn = fmaxf(m_, mg);
      float al = __builtin_amdgcn_exp2f((m_ - mn) * cexp);
      m_ = mn;
      ls *= al;
      #pragma unroll
      for (int dt = 0; dt < 2; ++dt)
        #pragma unroll
        for (int r = 0; r < 16; ++r) oa[dt][r] *= al;
    }
    const float mc = m_ * cexp;
    #pragma unroll
    for (int kt2 = 0; kt2 < 2; ++kt2)
      #pragma unroll
      for (int r = 0; r < 16; ++r)
        st[kt2][r] = __builtin_amdgcn_exp2f(fmaf(st[kt2][r], cexp, -mc));
    float s0[8];
    #pragma unroll
    for (int i = 0; i < 8; ++i)
      s0[i] = (st[0][i] + st[0][i + 8]) + (st[1][i] + st[1][i + 8]);
    ls += ((s0[0] + s0[1]) + (s0[2] + s0[3])) + ((s0[4] + s0[5]) + (s0[6] + s0[7]));
    // ---- pack P into PV B-frags via cvt_pk + permlane32_swap ----
    bf16x8 pfr[4];
    #pragma unroll
    for (int ks = 0; ks < 4; ++ks) {
      int tt = ks >> 1, gX = 2 * (ks & 1), gY = gX + 1;
      unsigned int x1 = cvtpk(st[tt][4 * gX + 0], st[tt][4 * gX + 1]);
      unsigned int y1 = cvtpk(st[tt][4 * gY + 0], st[tt][4 * gY + 1]);
      plswap(x1, y1);
      unsigned int x2 = cvtpk(st[tt][4 * gX + 2], st[tt][4 * gX + 3]);
      unsigned int y2 = cvtpk(st[tt][4 * gY + 2], st[tt][4 * gY + 3]);
      plswap(x2, y2);
      union { unsigned int u[4]; bf16x8 b; } cc;
      cc.u[0] = x1; cc.u[1] = x2; cc.u[2] = y1; cc.u[3] = y2;
      pfr[ks] = cc.b;
    }
    // ---- O^T += V^T P ----
    __builtin_amdgcn_s_setprio(1);
    #pragma unroll
    for (int dt = 0; dt < 2; ++dt)
      #pragma unroll
      for (int ks = 0; ks < 4; ++ks) {
        int vrow = dt * 32 + q31;
        bf16x8 vf = *(const bf16x8*)&Vl[cur][vrow * 64 + (((2 * ks + hi) ^ (vrow & 7)) * 8)];
        oa[dt] = __builtin_amdgcn_mfma_f32_32x32x16_bf16(vf, pfr[ks], oa[dt], 0, 0, 0);
      }
    __builtin_amdgcn_s_setprio(0);
  }
  // ---- epilogue: combine lane-pair ls, normalize, store ----
  float lt = ls + __shfl_xor(ls, 32, 64);
  float inv = 1.0f / lt;
  #pragma unroll
  for (int dt = 0; dt < 2; ++dt)
    #pragma unroll
    for (int g = 0; g < 4; ++g) {
      ushort4 o4;
      o4.x = f2bf(oa[dt][4 * g + 0] * inv);
      o4.y = f2bf(oa[dt][4 * g + 1] * inv);
      o4.z = f2bf(oa[dt][4 * g + 2] * inv);
      o4.w = f2bf(oa[dt][4 * g + 3] * inv);
      *(ushort4*)&O[qgrow * 1024 + h * 64 + dt * 32 + 8 * g + 4 * hi] = o4;
    }
}

// ---------------- launch ----------------
extern "C" void kernel_launch(void* const* d_in, const int* in_sizes, int n_in,
                              void* d_out, int out_size, void* d_ws, size_t ws_size,
                              hipStream_t stream) {
  const float* x  = (const float*)d_in[0];
  const float* Wq = (const float*)d_in[1];
  const float* Wk = (const float*)d_in[2];
  const float* Wv = (const float*)d_in[3];
  const float* Wo = (const float*)d_in[4];
  char* ws = (char*)d_ws;
  unsigned short* xb   = (unsigned short*)(ws);                    // 8 MiB (x bf16; later reused as Vt)
  unsigned short* Wb   = (unsigned short*)(ws + (8u << 20));       // 6 MiB
  unsigned short* Wob  = (unsigned short*)(ws + (14u << 20));      // 2 MiB
  unsigned short* QKVb = (unsigned short*)(ws + (16u << 20));      // 24 MiB
  unsigned short* Ob   = (unsigned short*)(ws + (40u << 20));      // 8 MiB
  unsigned short* Vtg  = xb;                                       // reuse: x dead after QKV GEMM

  cvt_k<<<4096, 256, 0, stream>>>(x, xb, 4096 * 1024 / 4);
  cvt_k<<<1024, 256, 0, stream>>>(Wq, Wb, 1024 * 1024 / 4);
  cvt_k<<<1024, 256, 0, stream>>>(Wk, Wb + 1024 * 1024, 1024 * 1024 / 4);
  cvt_k<<<1024, 256, 0, stream>>>(Wv, Wb + 2 * 1024 * 1024, 1024 * 1024 / 4);
  cvt_k<<<1024, 256, 0, stream>>>(Wo, Wob, 1024 * 1024 / 4);

  gemm_bt<0><<<dim3(32, 24), 256, 0, stream>>>(xb, Wb, QKVb, 3072, 1024);
  rope_k<<<4096, 256, 0, stream>>>(QKVb);
  vtr_k<<<dim3(32, 32), 256, 0, stream>>>(QKVb, Vtg);
  attn_k<<<dim3(32, 32), 128, 0, stream>>>(QKVb, Vtg, Ob);
  gemm_bt<1><<<dim3(32, 8), 256, 0, stream>>>(Ob, Wob, d_out, 1024, 1024);
}

// Round 11
// 133.121 us; speedup vs baseline: 2.1262x; 1.0042x over previous
//
#include <hip/hip_runtime.h>

typedef __attribute__((ext_vector_type(8))) short bf16x8;
typedef __attribute__((ext_vector_type(4))) float f32x4;
typedef __attribute__((ext_vector_type(16))) float f32x16;

typedef const __attribute__((address_space(1))) unsigned int gu32;
typedef __attribute__((address_space(3))) unsigned int lu32;

__device__ __forceinline__ void async16(const void* g, void* l) {
  __builtin_amdgcn_global_load_lds((gu32*)g, (lu32*)l, 16, 0, 0);
}

__device__ __forceinline__ unsigned short f2bf(float f) {
  unsigned int u = __float_as_uint(f);
  u += 0x7fffu + ((u >> 16) & 1u);
  return (unsigned short)(u >> 16);
}
__device__ __forceinline__ float b2f(unsigned short s) {
  return __uint_as_float(((unsigned int)s) << 16);
}
__device__ __forceinline__ unsigned int cvtpk(float lo, float hi) {
  unsigned int w;
  asm("v_cvt_pk_bf16_f32 %0, %1, %2" : "=v"(w) : "v"(lo), "v"(hi));
  return w;
}
__device__ __forceinline__ void plswap(unsigned int& x, unsigned int& y) {
  asm("v_permlane32_swap_b32 %0, %1" : "+v"(x), "+v"(y));
}

// ---------------- fp32 -> bf16 conversion ----------------
__global__ __launch_bounds__(256) void cvt_k(const float* __restrict__ in,
                                             unsigned short* __restrict__ out,
                                             int n4) {
  int i = blockIdx.x * 256 + threadIdx.x;
  if (i >= n4) return;
  float4 v = ((const float4*)in)[i];
  ushort4 o;
  o.x = f2bf(v.x); o.y = f2bf(v.y); o.z = f2bf(v.z); o.w = f2bf(v.w);
  ((ushort4*)out)[i] = o;
}

// ---------------- GEMM: C[m][n] = sum_k A[m][k] * B[n][k] ----------------
// (R10, unchanged) 128x128 tile, BK=32 double-buffered, depth-1 pipeline.
template <int WRITE_F32>
__global__ __launch_bounds__(256) void gemm_bt(const unsigned short* __restrict__ A,
                                               const unsigned short* __restrict__ B,
                                               void* __restrict__ Cp, int N, int K) {
  __shared__ __align__(16) unsigned short Al[2][128 * 32];
  __shared__ __align__(16) unsigned short Bl[2][128 * 32];
  const int t = threadIdx.x;
  const int w = t >> 6, l = t & 63;
  const int wm = w >> 1, wn = w & 1;
  const int lr = l & 15, lg = l >> 4;
  const long bm = (long)blockIdx.x * 128, bn = (long)blockIdx.y * 128;
  const int srow = t >> 2;                 // 0..63 (4 threads per row)
  const int c8 = t & 3;                    // 16B chunk within the 32-elem row
  const int KT = K >> 5;
  f32x4 acc[4][4] = {};

  auto STAGE = [&](int ts) {   // 4 async16 per thread (2 A + 2 B)
    const int bi = ts & 1;
    const int k0 = ts * 32;
    #pragma unroll
    for (int r = 0; r < 2; ++r) {
      int row = r * 64 + srow;
      async16(&A[(bm + row) * (long)K + k0 + c8 * 8], &Al[bi][row * 32 + c8 * 8]);
      async16(&B[(bn + row) * (long)K + k0 + c8 * 8], &Bl[bi][row * 32 + c8 * 8]);
    }
  };

  STAGE(0);
  for (int kt = 0; kt < KT; ++kt) {
    const int cur = kt & 1;
    asm volatile("s_waitcnt vmcnt(0)" ::: "memory");  // tile kt landed
    __builtin_amdgcn_s_barrier();                     // all waves; prev readers done
    __builtin_amdgcn_sched_barrier(0);
    if (kt + 1 < KT) STAGE(kt + 1);                   // prefetch into other buffer
    bf16x8 af[4], bf[4];
    #pragma unroll
    for (int i = 0; i < 4; ++i) {
      af[i] = *(const bf16x8*)&Al[cur][(wm * 64 + i * 16 + lr) * 32 + lg * 8];
      bf[i] = *(const bf16x8*)&Bl[cur][(wn * 64 + i * 16 + lr) * 32 + lg * 8];
    }
    #pragma unroll
    for (int i = 0; i < 4; ++i)
      #pragma unroll
      for (int j = 0; j < 4; ++j)
        acc[i][j] = __builtin_amdgcn_mfma_f32_16x16x32_bf16(af[i], bf[j], acc[i][j], 0, 0, 0);
  }
  #pragma unroll
  for (int i = 0; i < 4; ++i)
    #pragma unroll
    for (int j = 0; j < 4; ++j)
      #pragma unroll
      for (int r = 0; r < 4; ++r) {
        long row = bm + wm * 64 + i * 16 + lg * 4 + r;
        long col = bn + wn * 64 + j * 16 + lr;
        float v = acc[i][j][r];
        if (WRITE_F32) ((float*)Cp)[row * N + col] = v;
        else ((unsigned short*)Cp)[row * N + col] = f2bf(v);
      }
}

// ---------------- RoPE in-place, table-per-row (R10, unchanged) ----------
__global__ __launch_bounds__(256) void rope_k(unsigned short* __restrict__ QKV) {
  __shared__ float csl[32], snl[32];
  const int row = blockIdx.x;
  const int s = row & 2047;
  const int t = threadIdx.x;
  if (t < 32) {
    float invf = exp2f((float)t * (-13.287712379549449f / 32.0f));
    float sn, cs;
    sincosf((float)s * invf, &sn, &cs);
    csl[t] = cs; snl[t] = sn;
  }
  __syncthreads();
  const int col0 = (t < 128) ? t * 8 : 1024 + (t - 128) * 8;
  const int i0 = (t & 7) * 4;
  unsigned short* p = &QKV[(size_t)row * 3072 + col0];
  bf16x8 v = *(const bf16x8*)p;
  bf16x8 o;
  #pragma unroll
  for (int j = 0; j < 4; ++j) {
    float x1 = b2f((unsigned short)v[2 * j]);
    float x2 = b2f((unsigned short)v[2 * j + 1]);
    float cs = csl[i0 + j], sn = snl[i0 + j];
    o[2 * j]     = (short)f2bf(x1 * cs - x2 * sn);
    o[2 * j + 1] = (short)f2bf(x1 * sn + x2 * cs);
  }
  *(bf16x8*)p = o;
}

// ---------------- V transpose (R10, unchanged) ----------
__global__ __launch_bounds__(256) void vtr_k(const unsigned short* __restrict__ QKV,
                                             unsigned short* __restrict__ Vt) {
  __shared__ unsigned short tl[64][66];
  const int kt = blockIdx.x;            // k-tile 0..31
  const int bh = blockIdx.y;            // 0..31
  const int b = bh >> 4, h = bh & 15;
  const int t = threadIdx.x;
  const int row = t >> 3, c8 = t & 7;
  #pragma unroll
  for (int r = 0; r < 2; ++r) {
    int k = r * 32 + row;
    bf16x8 v = *(const bf16x8*)&QKV[((long)b * 2048 + kt * 64 + k) * 3072 + 2048 + h * 64 + c8 * 8];
    #pragma unroll
    for (int j = 0; j < 8; ++j) tl[c8 * 8 + j][k] = (unsigned short)v[j];
  }
  __syncthreads();
  #pragma unroll
  for (int r = 0; r < 2; ++r) {
    int d = r * 32 + row;
    ushort4 a, bq;
    a.x = tl[d][c8 * 8 + 0]; a.y = tl[d][c8 * 8 + 1];
    a.z = tl[d][c8 * 8 + 2]; a.w = tl[d][c8 * 8 + 3];
    bq.x = tl[d][c8 * 8 + 4]; bq.y = tl[d][c8 * 8 + 5];
    bq.z = tl[d][c8 * 8 + 6]; bq.w = tl[d][c8 * 8 + 7];
    long off = ((long)bh * 64 + d) * 2048 + kt * 64 + c8 * 8;
    *(ushort4*)&Vt[off] = a;
    *(ushort4*)&Vt[off + 4] = bq;
  }
}

// ---------------- causal flash attention ----------------
// 128 q-rows/block, 4 waves (32 rows each), 256 threads. Halves the total
// tile-step count (8704 vs 16896) at the same MFMA work, and puts 8 waves/CU.
// Swapped-QK^T 32x32; K/V^T staged via global_load_lds + XOR swizzle (8-row
// wave-contiguous groups: LDS dest = base + 16*lane per instr). 2-buffer
// depth-1 pipeline. Per-wave ktmax skips fully-masked tiles. XCD clustering
// via grid.x = bh.
__global__ __launch_bounds__(256) void attn_k(const unsigned short* __restrict__ QKV,
                                              const unsigned short* __restrict__ VtG,
                                              unsigned short* __restrict__ O) {
  __shared__ __align__(16) unsigned short Kl[2][64 * 64];   // K tile [k][d], swz
  __shared__ __align__(16) unsigned short Vl[2][64 * 64];   // V^T tile [d][k], swz
  const int t = threadIdx.x;
  const int w = t >> 6, l = t & 63;
  const int q31 = l & 31, hi = l >> 5;
  const int bh = blockIdx.x;               // same head -> same XCD
  const int qt = 15 - (int)blockIdx.y;     // LPT: longest first
  const int b = bh >> 4, h = bh & 15;
  const int Qb = qt * 128;
  const long rowb = (long)b * 2048;
  const int L = 3072;
  const int NT = 2 * qt + 2;
  const float cexp = 0.125f * 1.4426950408889634f;

  const int qmy = Qb + 32 * w + q31;
  const long qgrow = rowb + qmy;
  const int ktmax = (Qb + 32 * w) >> 6;    // wave-uniform last useful tile

  bf16x8 qf[4];
  #pragma unroll
  for (int dk = 0; dk < 4; ++dk)
    qf[dk] = *(const bf16x8*)&QKV[qgrow * L + h * 64 + dk * 16 + hi * 8];

  float m_ = -1e30f, ls = 0.0f;            // ls: per-lane partial (own 32 cols)
  f32x16 oa[2];
  #pragma unroll
  for (int dt = 0; dt < 2; ++dt)
    #pragma unroll
    for (int r = 0; r < 16; ++r) oa[dt][r] = 0.0f;

  auto STAGE = [&](int ts) {   // 4 async16 per thread (2 K + 2 V)
    const int bi = ts & 1;
    const long kb = rowb + (long)ts * 64;
    const long vrowb = (long)bh * 64;
    #pragma unroll
    for (int r = 0; r < 2; ++r) {
      int row = w * 16 + r * 8 + (l >> 3);           // wave-contiguous 8-row group
      int c8s = ((l & 7) ^ (row & 7)) * 8;           // pre-swizzled global col
      async16(&QKV[(kb + row) * L + 1024 + h * 64 + c8s], &Kl[bi][row * 64 + (l & 7) * 8]);
      async16(&VtG[(vrowb + row) * 2048 + ts * 64 + c8s], &Vl[bi][row * 64 + (l & 7) * 8]);
    }
  };

  STAGE(0);

  for (int kt = 0; kt < NT; ++kt) {
    const int cur = kt & 1;
    asm volatile("s_waitcnt vmcnt(0)" ::: "memory");   // tile kt landed
    __builtin_amdgcn_s_barrier();                      // prev readers done too
    __builtin_amdgcn_sched_barrier(0);
    if (kt + 1 < NT) STAGE(kt + 1);

    if (kt <= ktmax) {
      // ---- S^T = K Q^T ----
      f32x16 st[2];
      #pragma unroll
      for (int kt2 = 0; kt2 < 2; ++kt2)
        #pragma unroll
        for (int r = 0; r < 16; ++r) st[kt2][r] = 0.0f;
      __builtin_amdgcn_s_setprio(1);
      #pragma unroll
      for (int dk = 0; dk < 4; ++dk)
        #pragma unroll
        for (int kt2 = 0; kt2 < 2; ++kt2) {
          int krow = kt2 * 32 + q31;
          bf16x8 kfr = *(const bf16x8*)&Kl[cur][krow * 64 + (((2 * dk + hi) ^ (krow & 7)) * 8)];
          st[kt2] = __builtin_amdgcn_mfma_f32_32x32x16_bf16(kfr, qf[dk], st[kt2], 0, 0, 0);
        }
      __builtin_amdgcn_s_setprio(0);
      if (kt == ktmax) {
        #pragma unroll
        for (int kt2 = 0; kt2 < 2; ++kt2)
          #pragma unroll
          for (int r = 0; r < 16; ++r) {
            int kg = kt * 64 + kt2 * 32 + (r & 3) + 8 * (r >> 2) + 4 * hi;
            if (kg > qmy) st[kt2][r] = -1e30f;
          }
      }
      // ---- online softmax: per-lane max; shfl only when rescaling ----
      float m0[8];
      #pragma unroll
      for (int i = 0; i < 8; ++i)
        m0[i] = fmaxf(fmaxf(st[0][i], st[0][i + 8]), fmaxf(st[1][i], st[1][i + 8]));
      float mt = fmaxf(fmaxf(fmaxf(m0[0], m0[1]), fmaxf(m0[2], m0[3])),
                       fmaxf(fmaxf(m0[4], m0[5]), fmaxf(m0[6], m0[7])));
      if (__any((mt - m_) * cexp > 8.0f)) {   // defer-max (T13)
        float mg = fmaxf(mt, __shfl_xor(mt, 32, 64));   // row max (pair-synced)
        float mn = fmaxf(m_, mg);
        float al = __builtin_amdgcn_exp2f((m_ - mn) * cexp);
        m_ = mn;
        ls *= al;
        #pragma unroll
        for (int dt = 0; dt < 2; ++dt)
          #pragma unroll
          for (int r = 0; r < 16; ++r) oa[dt][r] *= al;
      }
      const float mc = m_ * cexp;
      #pragma unroll
      for (int kt2 = 0; kt2 < 2; ++kt2)
        #pragma unroll
        for (int r = 0; r < 16; ++r)
          st[kt2][r] = __builtin_amdgcn_exp2f(fmaf(st[kt2][r], cexp, -mc));
      float s0[8];
      #pragma unroll
      for (int i = 0; i < 8; ++i)
        s0[i] = (st[0][i] + st[0][i + 8]) + (st[1][i] + st[1][i + 8]);
      ls += ((s0[0] + s0[1]) + (s0[2] + s0[3])) + ((s0[4] + s0[5]) + (s0[6] + s0[7]));
      // ---- pack P into PV B-frags via cvt_pk + permlane32_swap ----
      bf16x8 pfr[4];
      #pragma unroll
      for (int ks = 0; ks < 4; ++ks) {
        int tt = ks >> 1, gX = 2 * (ks & 1), gY = gX + 1;
        unsigned int x1 = cvtpk(st[tt][4 * gX + 0], st[tt][4 * gX + 1]);
        unsigned int y1 = cvtpk(st[tt][4 * gY + 0], st[tt][4 * gY + 1]);
        plswap(x1, y1);
        unsigned int x2 = cvtpk(st[tt][4 * gX + 2], st[tt][4 * gX + 3]);
        unsigned int y2 = cvtpk(st[tt][4 * gY + 2], st[tt][4 * gY + 3]);
        plswap(x2, y2);
        union { unsigned int u[4]; bf16x8 b; } cc;
        cc.u[0] = x1; cc.u[1] = x2; cc.u[2] = y1; cc.u[3] = y2;
        pfr[ks] = cc.b;
      }
      // ---- O^T += V^T P ----
      __builtin_amdgcn_s_setprio(1);
      #pragma unroll
      for (int dt = 0; dt < 2; ++dt)
        #pragma unroll
        for (int ks = 0; ks < 4; ++ks) {
          int vrow = dt * 32 + q31;
          bf16x8 vf = *(const bf16x8*)&Vl[cur][vrow * 64 + (((2 * ks + hi) ^ (vrow & 7)) * 8)];
          oa[dt] = __builtin_amdgcn_mfma_f32_32x32x16_bf16(vf, pfr[ks], oa[dt], 0, 0, 0);
        }
      __builtin_amdgcn_s_setprio(0);
    }
  }
  // ---- epilogue: combine lane-pair ls, normalize, store ----
  float lt = ls + __shfl_xor(ls, 32, 64);
  float inv = 1.0f / lt;
  #pragma unroll
  for (int dt = 0; dt < 2; ++dt)
    #pragma unroll
    for (int g = 0; g < 4; ++g) {
      ushort4 o4;
      o4.x = f2bf(oa[dt][4 * g + 0] * inv);
      o4.y = f2bf(oa[dt][4 * g + 1] * inv);
      o4.z = f2bf(oa[dt][4 * g + 2] * inv);
      o4.w = f2bf(oa[dt][4 * g + 3] * inv);
      *(ushort4*)&O[qgrow * 1024 + h * 64 + dt * 32 + 8 * g + 4 * hi] = o4;
    }
}

// ---------------- launch ----------------
extern "C" void kernel_launch(void* const* d_in, const int* in_sizes, int n_in,
                              void* d_out, int out_size, void* d_ws, size_t ws_size,
                              hipStream_t stream) {
  const float* x  = (const float*)d_in[0];
  const float* Wq = (const float*)d_in[1];
  const float* Wk = (const float*)d_in[2];
  const float* Wv = (const float*)d_in[3];
  const float* Wo = (const float*)d_in[4];
  char* ws = (char*)d_ws;
  unsigned short* xb   = (unsigned short*)(ws);                    // 8 MiB (x bf16; later reused as Vt)
  unsigned short* Wb   = (unsigned short*)(ws + (8u << 20));       // 6 MiB
  unsigned short* Wob  = (unsigned short*)(ws + (14u << 20));      // 2 MiB
  unsigned short* QKVb = (unsigned short*)(ws + (16u << 20));      // 24 MiB
  unsigned short* Ob   = (unsigned short*)(ws + (40u << 20));      // 8 MiB
  unsigned short* Vtg  = xb;                                       // reuse: x dead after QKV GEMM

  cvt_k<<<4096, 256, 0, stream>>>(x, xb, 4096 * 1024 / 4);
  cvt_k<<<1024, 256, 0, stream>>>(Wq, Wb, 1024 * 1024 / 4);
  cvt_k<<<1024, 256, 0, stream>>>(Wk, Wb + 1024 * 1024, 1024 * 1024 / 4);
  cvt_k<<<1024, 256, 0, stream>>>(Wv, Wb + 2 * 1024 * 1024, 1024 * 1024 / 4);
  cvt_k<<<1024, 256, 0, stream>>>(Wo, Wob, 1024 * 1024 / 4);

  gemm_bt<0><<<dim3(32, 24), 256, 0, stream>>>(xb, Wb, QKVb, 3072, 1024);
  rope_k<<<4096, 256, 0, stream>>>(QKVb);
  vtr_k<<<dim3(32, 32), 256, 0, stream>>>(QKVb, Vtg);
  attn_k<<<dim3(32, 16), 256, 0, stream>>>(QKVb, Vtg, Ob);
  gemm_bt<1><<<dim3(32, 8), 256, 0, stream>>>(Ob, Wob, d_out, 1024, 1024);
}

// Round 12
// 130.984 us; speedup vs baseline: 2.1608x; 1.0163x over previous
//
#include <hip/hip_runtime.h>

typedef __attribute__((ext_vector_type(8))) short bf16x8;
typedef __attribute__((ext_vector_type(4))) float f32x4;
typedef __attribute__((ext_vector_type(16))) float f32x16;

typedef const __attribute__((address_space(1))) unsigned int gu32;
typedef __attribute__((address_space(3))) unsigned int lu32;

__device__ __forceinline__ void async16(const void* g, void* l) {
  __builtin_amdgcn_global_load_lds((gu32*)g, (lu32*)l, 16, 0, 0);
}

__device__ __forceinline__ unsigned short f2bf(float f) {
  unsigned int u = __float_as_uint(f);
  u += 0x7fffu + ((u >> 16) & 1u);
  return (unsigned short)(u >> 16);
}
__device__ __forceinline__ float b2f(unsigned short s) {
  return __uint_as_float(((unsigned int)s) << 16);
}
__device__ __forceinline__ unsigned int cvtpk(float lo, float hi) {
  unsigned int w;
  asm("v_cvt_pk_bf16_f32 %0, %1, %2" : "=v"(w) : "v"(lo), "v"(hi));
  return w;
}
__device__ __forceinline__ void plswap(unsigned int& x, unsigned int& y) {
  asm("v_permlane32_swap_b32 %0, %1" : "+v"(x), "+v"(y));
}

// ---------------- fp32 -> bf16 conversion ----------------
__global__ __launch_bounds__(256) void cvt_k(const float* __restrict__ in,
                                             unsigned short* __restrict__ out,
                                             int n4) {
  int i = blockIdx.x * 256 + threadIdx.x;
  if (i >= n4) return;
  float4 v = ((const float4*)in)[i];
  ushort4 o;
  o.x = f2bf(v.x); o.y = f2bf(v.y); o.z = f2bf(v.z); o.w = f2bf(v.w);
  ((ushort4*)out)[i] = o;
}

// ---------------- GEMM (R10, unchanged) ----------------
template <int WRITE_F32>
__global__ __launch_bounds__(256) void gemm_bt(const unsigned short* __restrict__ A,
                                               const unsigned short* __restrict__ B,
                                               void* __restrict__ Cp, int N, int K) {
  __shared__ __align__(16) unsigned short Al[2][128 * 32];
  __shared__ __align__(16) unsigned short Bl[2][128 * 32];
  const int t = threadIdx.x;
  const int w = t >> 6, l = t & 63;
  const int wm = w >> 1, wn = w & 1;
  const int lr = l & 15, lg = l >> 4;
  const long bm = (long)blockIdx.x * 128, bn = (long)blockIdx.y * 128;
  const int srow = t >> 2;                 // 0..63 (4 threads per row)
  const int c8 = t & 3;                    // 16B chunk within the 32-elem row
  const int KT = K >> 5;
  f32x4 acc[4][4] = {};

  auto STAGE = [&](int ts) {   // 4 async16 per thread (2 A + 2 B)
    const int bi = ts & 1;
    const int k0 = ts * 32;
    #pragma unroll
    for (int r = 0; r < 2; ++r) {
      int row = r * 64 + srow;
      async16(&A[(bm + row) * (long)K + k0 + c8 * 8], &Al[bi][row * 32 + c8 * 8]);
      async16(&B[(bn + row) * (long)K + k0 + c8 * 8], &Bl[bi][row * 32 + c8 * 8]);
    }
  };

  STAGE(0);
  for (int kt = 0; kt < KT; ++kt) {
    const int cur = kt & 1;
    asm volatile("s_waitcnt vmcnt(0)" ::: "memory");  // tile kt landed
    __builtin_amdgcn_s_barrier();                     // all waves; prev readers done
    __builtin_amdgcn_sched_barrier(0);
    if (kt + 1 < KT) STAGE(kt + 1);                   // prefetch into other buffer
    bf16x8 af[4], bf[4];
    #pragma unroll
    for (int i = 0; i < 4; ++i) {
      af[i] = *(const bf16x8*)&Al[cur][(wm * 64 + i * 16 + lr) * 32 + lg * 8];
      bf[i] = *(const bf16x8*)&Bl[cur][(wn * 64 + i * 16 + lr) * 32 + lg * 8];
    }
    #pragma unroll
    for (int i = 0; i < 4; ++i)
      #pragma unroll
      for (int j = 0; j < 4; ++j)
        acc[i][j] = __builtin_amdgcn_mfma_f32_16x16x32_bf16(af[i], bf[j], acc[i][j], 0, 0, 0);
  }
  #pragma unroll
  for (int i = 0; i < 4; ++i)
    #pragma unroll
    for (int j = 0; j < 4; ++j)
      #pragma unroll
      for (int r = 0; r < 4; ++r) {
        long row = bm + wm * 64 + i * 16 + lg * 4 + r;
        long col = bn + wn * 64 + j * 16 + lr;
        float v = acc[i][j][r];
        if (WRITE_F32) ((float*)Cp)[row * N + col] = v;
        else ((unsigned short*)Cp)[row * N + col] = f2bf(v);
      }
}

// ---------------- RoPE in-place, table-per-row (R10, unchanged) ----------
__global__ __launch_bounds__(256) void rope_k(unsigned short* __restrict__ QKV) {
  __shared__ float csl[32], snl[32];
  const int row = blockIdx.x;
  const int s = row & 2047;
  const int t = threadIdx.x;
  if (t < 32) {
    float invf = exp2f((float)t * (-13.287712379549449f / 32.0f));
    float sn, cs;
    sincosf((float)s * invf, &sn, &cs);
    csl[t] = cs; snl[t] = sn;
  }
  __syncthreads();
  const int col0 = (t < 128) ? t * 8 : 1024 + (t - 128) * 8;
  const int i0 = (t & 7) * 4;
  unsigned short* p = &QKV[(size_t)row * 3072 + col0];
  bf16x8 v = *(const bf16x8*)p;
  bf16x8 o;
  #pragma unroll
  for (int j = 0; j < 4; ++j) {
    float x1 = b2f((unsigned short)v[2 * j]);
    float x2 = b2f((unsigned short)v[2 * j + 1]);
    float cs = csl[i0 + j], sn = snl[i0 + j];
    o[2 * j]     = (short)f2bf(x1 * cs - x2 * sn);
    o[2 * j + 1] = (short)f2bf(x1 * sn + x2 * cs);
  }
  *(bf16x8*)p = o;
}

// ---------------- V transpose (R10, unchanged) ----------
__global__ __launch_bounds__(256) void vtr_k(const unsigned short* __restrict__ QKV,
                                             unsigned short* __restrict__ Vt) {
  __shared__ unsigned short tl[64][66];
  const int kt = blockIdx.x;            // k-tile 0..31
  const int bh = blockIdx.y;            // 0..31
  const int b = bh >> 4, h = bh & 15;
  const int t = threadIdx.x;
  const int row = t >> 3, c8 = t & 7;
  #pragma unroll
  for (int r = 0; r < 2; ++r) {
    int k = r * 32 + row;
    bf16x8 v = *(const bf16x8*)&QKV[((long)b * 2048 + kt * 64 + k) * 3072 + 2048 + h * 64 + c8 * 8];
    #pragma unroll
    for (int j = 0; j < 8; ++j) tl[c8 * 8 + j][k] = (unsigned short)v[j];
  }
  __syncthreads();
  #pragma unroll
  for (int r = 0; r < 2; ++r) {
    int d = r * 32 + row;
    ushort4 a, bq;
    a.x = tl[d][c8 * 8 + 0]; a.y = tl[d][c8 * 8 + 1];
    a.z = tl[d][c8 * 8 + 2]; a.w = tl[d][c8 * 8 + 3];
    bq.x = tl[d][c8 * 8 + 4]; bq.y = tl[d][c8 * 8 + 5];
    bq.z = tl[d][c8 * 8 + 6]; bq.w = tl[d][c8 * 8 + 7];
    long off = ((long)bh * 64 + d) * 2048 + kt * 64 + c8 * 8;
    *(ushort4*)&Vt[off] = a;
    *(ushort4*)&Vt[off + 4] = bq;
  }
}

// ---------------- causal flash attention ----------------
// 128 q-rows/block, 4 waves, 256 threads. Swapped-QK^T 32x32.
// Cross-tile pipeline (att[2]): at step kt, compute QK^T(kt+1) FIRST (matrix
// pipe), then softmax+pack+PV of tile kt (VALU pipe) — independent, so the
// scheduler interleaves them and the serial per-step chain collapses to
// ~max(QK, SM) + PV. 3 LDS buffers: step kt reads K[(kt+1)%3], V[kt%3],
// stages (kt+2)%3 — all distinct; each buffer's readers finish a full step
// before its next writer issues (barrier at step top). vmcnt(0) per step.
// Two named register tiles (stA/stB) + 2x-unrolled loop: no runtime indexing.
__global__ __launch_bounds__(256) void attn_k(const unsigned short* __restrict__ QKV,
                                              const unsigned short* __restrict__ VtG,
                                              unsigned short* __restrict__ O) {
  __shared__ __align__(16) unsigned short Kl[3][64 * 64];   // K tile [k][d], swz
  __shared__ __align__(16) unsigned short Vl[3][64 * 64];   // V^T tile [d][k], swz
  const int t = threadIdx.x;
  const int w = t >> 6, l = t & 63;
  const int q31 = l & 31, hi = l >> 5;
  const int bh = blockIdx.x;               // same head -> same XCD
  const int qt = 15 - (int)blockIdx.y;     // LPT: longest first
  const int b = bh >> 4, h = bh & 15;
  const int Qb = qt * 128;
  const long rowb = (long)b * 2048;
  const int L = 3072;
  const int NT = 2 * qt + 2;
  const float cexp = 0.125f * 1.4426950408889634f;

  const int qmy = Qb + 32 * w + q31;
  const long qgrow = rowb + qmy;
  const int ktmax = (Qb + 32 * w) >> 6;    // wave-uniform last useful tile

  bf16x8 qf[4];
  #pragma unroll
  for (int dk = 0; dk < 4; ++dk)
    qf[dk] = *(const bf16x8*)&QKV[qgrow * L + h * 64 + dk * 16 + hi * 8];

  float m_ = -1e30f, ls = 0.0f;            // ls: per-lane partial (own 32 cols)
  f32x16 oa[2];
  #pragma unroll
  for (int dt = 0; dt < 2; ++dt)
    #pragma unroll
    for (int r = 0; r < 16; ++r) oa[dt][r] = 0.0f;

  auto STAGE = [&](int ts) {   // 4 async16 per thread (2 K + 2 V)
    const int bi = ts % 3;
    const long kb = rowb + (long)ts * 64;
    const long vrowb = (long)bh * 64;
    #pragma unroll
    for (int r = 0; r < 2; ++r) {
      int row = w * 16 + r * 8 + (l >> 3);           // wave-contiguous 8-row group
      int c8s = ((l & 7) ^ (row & 7)) * 8;           // pre-swizzled global col
      async16(&QKV[(kb + row) * L + 1024 + h * 64 + c8s], &Kl[bi][row * 64 + (l & 7) * 8]);
      async16(&VtG[(vrowb + row) * 2048 + ts * 64 + c8s], &Vl[bi][row * 64 + (l & 7) * 8]);
    }
  };

  // QK^T of buffer bi into st (S^T: lane holds P[q=lane&31][32 cols])
  auto QK = [&](f32x16 (&st)[2], int bi) {
    #pragma unroll
    for (int kt2 = 0; kt2 < 2; ++kt2)
      #pragma unroll
      for (int r = 0; r < 16; ++r) st[kt2][r] = 0.0f;
    __builtin_amdgcn_s_setprio(1);
    #pragma unroll
    for (int dk = 0; dk < 4; ++dk)
      #pragma unroll
      for (int kt2 = 0; kt2 < 2; ++kt2) {
        int krow = kt2 * 32 + q31;
        bf16x8 kfr = *(const bf16x8*)&Kl[bi][krow * 64 + (((2 * dk + hi) ^ (krow & 7)) * 8)];
        st[kt2] = __builtin_amdgcn_mfma_f32_32x32x16_bf16(kfr, qf[dk], st[kt2], 0, 0, 0);
      }
    __builtin_amdgcn_s_setprio(0);
  };

  // softmax + P-pack + PV for tile kt (st consumed)
  auto SMPV = [&](f32x16 (&st)[2], int kt) {
    if (kt == ktmax) {
      #pragma unroll
      for (int kt2 = 0; kt2 < 2; ++kt2)
        #pragma unroll
        for (int r = 0; r < 16; ++r) {
          int kg = kt * 64 + kt2 * 32 + (r & 3) + 8 * (r >> 2) + 4 * hi;
          if (kg > qmy) st[kt2][r] = -1e30f;
        }
    }
    float m0[8];
    #pragma unroll
    for (int i = 0; i < 8; ++i)
      m0[i] = fmaxf(fmaxf(st[0][i], st[0][i + 8]), fmaxf(st[1][i], st[1][i + 8]));
    float mt = fmaxf(fmaxf(fmaxf(m0[0], m0[1]), fmaxf(m0[2], m0[3])),
                     fmaxf(fmaxf(m0[4], m0[5]), fmaxf(m0[6], m0[7])));
    if (__any((mt - m_) * cexp > 8.0f)) {   // defer-max (T13)
      float mg = fmaxf(mt, __shfl_xor(mt, 32, 64));   // row max (pair-synced)
      float mn = fmaxf(m_, mg);
      float al = __builtin_amdgcn_exp2f((m_ - mn) * cexp);
      m_ = mn;
      ls *= al;
      #pragma unroll
      for (int dt = 0; dt < 2; ++dt)
        #pragma unroll
        for (int r = 0; r < 16; ++r) oa[dt][r] *= al;
    }
    const float mc = m_ * cexp;
    #pragma unroll
    for (int kt2 = 0; kt2 < 2; ++kt2)
      #pragma unroll
      for (int r = 0; r < 16; ++r)
        st[kt2][r] = __builtin_amdgcn_exp2f(fmaf(st[kt2][r], cexp, -mc));
    float s0[8];
    #pragma unroll
    for (int i = 0; i < 8; ++i)
      s0[i] = (st[0][i] + st[0][i + 8]) + (st[1][i] + st[1][i + 8]);
    ls += ((s0[0] + s0[1]) + (s0[2] + s0[3])) + ((s0[4] + s0[5]) + (s0[6] + s0[7]));
    bf16x8 pfr[4];
    #pragma unroll
    for (int ks = 0; ks < 4; ++ks) {
      int tt = ks >> 1, gX = 2 * (ks & 1), gY = gX + 1;
      unsigned int x1 = cvtpk(st[tt][4 * gX + 0], st[tt][4 * gX + 1]);
      unsigned int y1 = cvtpk(st[tt][4 * gY + 0], st[tt][4 * gY + 1]);
      plswap(x1, y1);
      unsigned int x2 = cvtpk(st[tt][4 * gX + 2], st[tt][4 * gX + 3]);
      unsigned int y2 = cvtpk(st[tt][4 * gY + 2], st[tt][4 * gY + 3]);
      plswap(x2, y2);
      union { unsigned int u[4]; bf16x8 b; } cc;
      cc.u[0] = x1; cc.u[1] = x2; cc.u[2] = y1; cc.u[3] = y2;
      pfr[ks] = cc.b;
    }
    const int vb = kt % 3;
    __builtin_amdgcn_s_setprio(1);
    #pragma unroll
    for (int dt = 0; dt < 2; ++dt)
      #pragma unroll
      for (int ks = 0; ks < 4; ++ks) {
        int vrow = dt * 32 + q31;
        bf16x8 vf = *(const bf16x8*)&Vl[vb][vrow * 64 + (((2 * ks + hi) ^ (vrow & 7)) * 8)];
        oa[dt] = __builtin_amdgcn_mfma_f32_32x32x16_bf16(vf, pfr[ks], oa[dt], 0, 0, 0);
      }
    __builtin_amdgcn_s_setprio(0);
  };

  f32x16 stA[2], stB[2];

  // prologue: tiles 0 and 1 in flight; compute S(0) once tile 0 lands
  STAGE(0);
  STAGE(1);
  asm volatile("s_waitcnt vmcnt(4)" ::: "memory");   // stage(0) landed (Q loads older)
  __builtin_amdgcn_s_barrier();
  __builtin_amdgcn_sched_barrier(0);
  QK(stA, 0);

  // one pipeline step: QK(kt+1) first, then SMPV(kt)
  auto STEP = [&](f32x16 (&cur)[2], f32x16 (&nxt)[2], int kt) {
    asm volatile("s_waitcnt vmcnt(0)" ::: "memory"); // stage(kt+1) landed
    __builtin_amdgcn_s_barrier();                    // all waves done with step kt-1
    __builtin_amdgcn_sched_barrier(0);
    if (kt + 1 < NT && kt + 1 <= ktmax) QK(nxt, (kt + 1) % 3);
    if (kt + 2 < NT) STAGE(kt + 2);
    if (kt <= ktmax) SMPV(cur, kt);
  };

  int kt = 0;
  while (kt < NT) {
    STEP(stA, stB, kt); ++kt;
    if (kt < NT) { STEP(stB, stA, kt); ++kt; }
  }

  // ---- epilogue: combine lane-pair ls, normalize, store ----
  float lt = ls + __shfl_xor(ls, 32, 64);
  float inv = 1.0f / lt;
  #pragma unroll
  for (int dt = 0; dt < 2; ++dt)
    #pragma unroll
    for (int g = 0; g < 4; ++g) {
      ushort4 o4;
      o4.x = f2bf(oa[dt][4 * g + 0] * inv);
      o4.y = f2bf(oa[dt][4 * g + 1] * inv);
      o4.z = f2bf(oa[dt][4 * g + 2] * inv);
      o4.w = f2bf(oa[dt][4 * g + 3] * inv);
      *(ushort4*)&O[qgrow * 1024 + h * 64 + dt * 32 + 8 * g + 4 * hi] = o4;
    }
}

// ---------------- launch ----------------
extern "C" void kernel_launch(void* const* d_in, const int* in_sizes, int n_in,
                              void* d_out, int out_size, void* d_ws, size_t ws_size,
                              hipStream_t stream) {
  const float* x  = (const float*)d_in[0];
  const float* Wq = (const float*)d_in[1];
  const float* Wk = (const float*)d_in[2];
  const float* Wv = (const float*)d_in[3];
  const float* Wo = (const float*)d_in[4];
  char* ws = (char*)d_ws;
  unsigned short* xb   = (unsigned short*)(ws);                    // 8 MiB (x bf16; later reused as Vt)
  unsigned short* Wb   = (unsigned short*)(ws + (8u << 20));       // 6 MiB
  unsigned short* Wob  = (unsigned short*)(ws + (14u << 20));      // 2 MiB
  unsigned short* QKVb = (unsigned short*)(ws + (16u << 20));      // 24 MiB
  unsigned short* Ob   = (unsigned short*)(ws + (40u << 20));      // 8 MiB
  unsigned short* Vtg  = xb;                                       // reuse: x dead after QKV GEMM

  cvt_k<<<4096, 256, 0, stream>>>(x, xb, 4096 * 1024 / 4);
  cvt_k<<<1024, 256, 0, stream>>>(Wq, Wb, 1024 * 1024 / 4);
  cvt_k<<<1024, 256, 0, stream>>>(Wk, Wb + 1024 * 1024, 1024 * 1024 / 4);
  cvt_k<<<1024, 256, 0, stream>>>(Wv, Wb + 2 * 1024 * 1024, 1024 * 1024 / 4);
  cvt_k<<<1024, 256, 0, stream>>>(Wo, Wob, 1024 * 1024 / 4);

  gemm_bt<0><<<dim3(32, 24), 256, 0, stream>>>(xb, Wb, QKVb, 3072, 1024);
  rope_k<<<4096, 256, 0, stream>>>(QKVb);
  vtr_k<<<dim3(32, 32), 256, 0, stream>>>(QKVb, Vtg);
  attn_k<<<dim3(32, 16), 256, 0, stream>>>(QKVb, Vtg, Ob);
  gemm_bt<1><<<dim3(32, 8), 256, 0, stream>>>(Ob, Wob, d_out, 1024, 1024);
}

// Round 13
// 130.363 us; speedup vs baseline: 2.1711x; 1.0048x over previous
//
#include <hip/hip_runtime.h>

typedef __attribute__((ext_vector_type(8))) short bf16x8;
typedef __attribute__((ext_vector_type(4))) float f32x4;
typedef __attribute__((ext_vector_type(16))) float f32x16;

typedef const __attribute__((address_space(1))) unsigned int gu32;
typedef __attribute__((address_space(3))) unsigned int lu32;

__device__ __forceinline__ void async16(const void* g, void* l) {
  __builtin_amdgcn_global_load_lds((gu32*)g, (lu32*)l, 16, 0, 0);
}

__device__ __forceinline__ unsigned short f2bf(float f) {
  unsigned int u = __float_as_uint(f);
  u += 0x7fffu + ((u >> 16) & 1u);
  return (unsigned short)(u >> 16);
}
__device__ __forceinline__ float b2f(unsigned short s) {
  return __uint_as_float(((unsigned int)s) << 16);
}
__device__ __forceinline__ unsigned int cvtpk(float lo, float hi) {
  unsigned int w;
  asm("v_cvt_pk_bf16_f32 %0, %1, %2" : "=v"(w) : "v"(lo), "v"(hi));
  return w;
}
__device__ __forceinline__ void plswap(unsigned int& x, unsigned int& y) {
  asm("v_permlane32_swap_b32 %0, %1" : "+v"(x), "+v"(y));
}
__device__ __forceinline__ float max3f(float a, float b, float c) {
  float d;
  asm("v_max3_f32 %0, %1, %2, %3" : "=v"(d) : "v"(a), "v"(b), "v"(c));
  return d;
}

// ---------------- fp32 -> bf16 conversion ----------------
__global__ __launch_bounds__(256) void cvt_k(const float* __restrict__ in,
                                             unsigned short* __restrict__ out,
                                             int n4) {
  int i = blockIdx.x * 256 + threadIdx.x;
  if (i >= n4) return;
  float4 v = ((const float4*)in)[i];
  ushort4 o;
  o.x = f2bf(v.x); o.y = f2bf(v.y); o.z = f2bf(v.z); o.w = f2bf(v.w);
  ((ushort4*)out)[i] = o;
}

// ---------------- GEMM (R10, unchanged) ----------------
template <int WRITE_F32>
__global__ __launch_bounds__(256) void gemm_bt(const unsigned short* __restrict__ A,
                                               const unsigned short* __restrict__ B,
                                               void* __restrict__ Cp, int N, int K) {
  __shared__ __align__(16) unsigned short Al[2][128 * 32];
  __shared__ __align__(16) unsigned short Bl[2][128 * 32];
  const int t = threadIdx.x;
  const int w = t >> 6, l = t & 63;
  const int wm = w >> 1, wn = w & 1;
  const int lr = l & 15, lg = l >> 4;
  const long bm = (long)blockIdx.x * 128, bn = (long)blockIdx.y * 128;
  const int srow = t >> 2;                 // 0..63 (4 threads per row)
  const int c8 = t & 3;                    // 16B chunk within the 32-elem row
  const int KT = K >> 5;
  f32x4 acc[4][4] = {};

  auto STAGE = [&](int ts) {   // 4 async16 per thread (2 A + 2 B)
    const int bi = ts & 1;
    const int k0 = ts * 32;
    #pragma unroll
    for (int r = 0; r < 2; ++r) {
      int row = r * 64 + srow;
      async16(&A[(bm + row) * (long)K + k0 + c8 * 8], &Al[bi][row * 32 + c8 * 8]);
      async16(&B[(bn + row) * (long)K + k0 + c8 * 8], &Bl[bi][row * 32 + c8 * 8]);
    }
  };

  STAGE(0);
  for (int kt = 0; kt < KT; ++kt) {
    const int cur = kt & 1;
    asm volatile("s_waitcnt vmcnt(0)" ::: "memory");  // tile kt landed
    __builtin_amdgcn_s_barrier();                     // all waves; prev readers done
    __builtin_amdgcn_sched_barrier(0);
    if (kt + 1 < KT) STAGE(kt + 1);                   // prefetch into other buffer
    bf16x8 af[4], bf[4];
    #pragma unroll
    for (int i = 0; i < 4; ++i) {
      af[i] = *(const bf16x8*)&Al[cur][(wm * 64 + i * 16 + lr) * 32 + lg * 8];
      bf[i] = *(const bf16x8*)&Bl[cur][(wn * 64 + i * 16 + lr) * 32 + lg * 8];
    }
    #pragma unroll
    for (int i = 0; i < 4; ++i)
      #pragma unroll
      for (int j = 0; j < 4; ++j)
        acc[i][j] = __builtin_amdgcn_mfma_f32_16x16x32_bf16(af[i], bf[j], acc[i][j], 0, 0, 0);
  }
  #pragma unroll
  for (int i = 0; i < 4; ++i)
    #pragma unroll
    for (int j = 0; j < 4; ++j)
      #pragma unroll
      for (int r = 0; r < 4; ++r) {
        long row = bm + wm * 64 + i * 16 + lg * 4 + r;
        long col = bn + wn * 64 + j * 16 + lr;
        float v = acc[i][j][r];
        if (WRITE_F32) ((float*)Cp)[row * N + col] = v;
        else ((unsigned short*)Cp)[row * N + col] = f2bf(v);
      }
}

// ---------------- RoPE in-place, table-per-row (R10, unchanged) ----------
__global__ __launch_bounds__(256) void rope_k(unsigned short* __restrict__ QKV) {
  __shared__ float csl[32], snl[32];
  const int row = blockIdx.x;
  const int s = row & 2047;
  const int t = threadIdx.x;
  if (t < 32) {
    float invf = exp2f((float)t * (-13.287712379549449f / 32.0f));
    float sn, cs;
    sincosf((float)s * invf, &sn, &cs);
    csl[t] = cs; snl[t] = sn;
  }
  __syncthreads();
  const int col0 = (t < 128) ? t * 8 : 1024 + (t - 128) * 8;
  const int i0 = (t & 7) * 4;
  unsigned short* p = &QKV[(size_t)row * 3072 + col0];
  bf16x8 v = *(const bf16x8*)p;
  bf16x8 o;
  #pragma unroll
  for (int j = 0; j < 4; ++j) {
    float x1 = b2f((unsigned short)v[2 * j]);
    float x2 = b2f((unsigned short)v[2 * j + 1]);
    float cs = csl[i0 + j], sn = snl[i0 + j];
    o[2 * j]     = (short)f2bf(x1 * cs - x2 * sn);
    o[2 * j + 1] = (short)f2bf(x1 * sn + x2 * cs);
  }
  *(bf16x8*)p = o;
}

// ---------------- V transpose (R10, unchanged) ----------
__global__ __launch_bounds__(256) void vtr_k(const unsigned short* __restrict__ QKV,
                                             unsigned short* __restrict__ Vt) {
  __shared__ unsigned short tl[64][66];
  const int kt = blockIdx.x;            // k-tile 0..31
  const int bh = blockIdx.y;            // 0..31
  const int b = bh >> 4, h = bh & 15;
  const int t = threadIdx.x;
  const int row = t >> 3, c8 = t & 7;
  #pragma unroll
  for (int r = 0; r < 2; ++r) {
    int k = r * 32 + row;
    bf16x8 v = *(const bf16x8*)&QKV[((long)b * 2048 + kt * 64 + k) * 3072 + 2048 + h * 64 + c8 * 8];
    #pragma unroll
    for (int j = 0; j < 8; ++j) tl[c8 * 8 + j][k] = (unsigned short)v[j];
  }
  __syncthreads();
  #pragma unroll
  for (int r = 0; r < 2; ++r) {
    int d = r * 32 + row;
    ushort4 a, bq;
    a.x = tl[d][c8 * 8 + 0]; a.y = tl[d][c8 * 8 + 1];
    a.z = tl[d][c8 * 8 + 2]; a.w = tl[d][c8 * 8 + 3];
    bq.x = tl[d][c8 * 8 + 4]; bq.y = tl[d][c8 * 8 + 5];
    bq.z = tl[d][c8 * 8 + 6]; bq.w = tl[d][c8 * 8 + 7];
    long off = ((long)bh * 64 + d) * 2048 + kt * 64 + c8 * 8;
    *(ushort4*)&Vt[off] = a;
    *(ushort4*)&Vt[off + 4] = bq;
  }
}

// ---------------- causal flash attention ----------------
// R12 cross-tile pipeline +:
//  * balanced pairing: qt = y<8 ? 15-y : y-8 -> each CU's two resident
//    blocks total exactly 34 steps (was 48/20) -> no tail, steady 8 waves/CU.
//  * row-sum via MFMA (A=ones) on the idle matrix pipe: removes 31 VALU
//    adds/step/lane + epilogue shfl; la[0] is the online-rescaled row sum.
//  * v_max3_f32 tree: 31 -> 20 ops for the per-tile max.
__global__ __launch_bounds__(256) void attn_k(const unsigned short* __restrict__ QKV,
                                              const unsigned short* __restrict__ VtG,
                                              unsigned short* __restrict__ O) {
  __shared__ __align__(16) unsigned short Kl[3][64 * 64];   // K tile [k][d], swz
  __shared__ __align__(16) unsigned short Vl[3][64 * 64];   // V^T tile [d][k], swz
  const int t = threadIdx.x;
  const int w = t >> 6, l = t & 63;
  const int q31 = l & 31, hi = l >> 5;
  const int bh = blockIdx.x;               // same head -> same XCD
  const int y = (int)blockIdx.y;
  const int qt = (y < 8) ? (15 - y) : (y - 8);   // balanced long/short pairing
  const int b = bh >> 4, h = bh & 15;
  const int Qb = qt * 128;
  const long rowb = (long)b * 2048;
  const int L = 3072;
  const int NT = 2 * qt + 2;
  const float cexp = 0.125f * 1.4426950408889634f;

  const int qmy = Qb + 32 * w + q31;
  const long qgrow = rowb + qmy;
  const int ktmax = (Qb + 32 * w) >> 6;    // wave-uniform last useful tile

  bf16x8 qf[4];
  #pragma unroll
  for (int dk = 0; dk < 4; ++dk)
    qf[dk] = *(const bf16x8*)&QKV[qgrow * L + h * 64 + dk * 16 + hi * 8];

  bf16x8 onesf;
  #pragma unroll
  for (int j = 0; j < 8; ++j) onesf[j] = (short)0x3F80;   // bf16 1.0

  float m_ = -1e30f;
  f32x16 oa[2], la;
  #pragma unroll
  for (int r = 0; r < 16; ++r) { oa[0][r] = 0.0f; oa[1][r] = 0.0f; la[r] = 0.0f; }

  auto STAGE = [&](int ts) {   // 4 async16 per thread (2 K + 2 V)
    const int bi = ts % 3;
    const long kb = rowb + (long)ts * 64;
    const long vrowb = (long)bh * 64;
    #pragma unroll
    for (int r = 0; r < 2; ++r) {
      int row = w * 16 + r * 8 + (l >> 3);           // wave-contiguous 8-row group
      int c8s = ((l & 7) ^ (row & 7)) * 8;           // pre-swizzled global col
      async16(&QKV[(kb + row) * L + 1024 + h * 64 + c8s], &Kl[bi][row * 64 + (l & 7) * 8]);
      async16(&VtG[(vrowb + row) * 2048 + ts * 64 + c8s], &Vl[bi][row * 64 + (l & 7) * 8]);
    }
  };

  // QK^T of buffer bi into st (S^T: lane holds P[q=lane&31][32 cols])
  auto QK = [&](f32x16 (&st)[2], int bi) {
    #pragma unroll
    for (int kt2 = 0; kt2 < 2; ++kt2)
      #pragma unroll
      for (int r = 0; r < 16; ++r) st[kt2][r] = 0.0f;
    __builtin_amdgcn_s_setprio(1);
    #pragma unroll
    for (int dk = 0; dk < 4; ++dk)
      #pragma unroll
      for (int kt2 = 0; kt2 < 2; ++kt2) {
        int krow = kt2 * 32 + q31;
        bf16x8 kfr = *(const bf16x8*)&Kl[bi][krow * 64 + (((2 * dk + hi) ^ (krow & 7)) * 8)];
        st[kt2] = __builtin_amdgcn_mfma_f32_32x32x16_bf16(kfr, qf[dk], st[kt2], 0, 0, 0);
      }
    __builtin_amdgcn_s_setprio(0);
  };

  // softmax + P-pack + PV (+ l via MFMA) for tile kt
  auto SMPV = [&](f32x16 (&st)[2], int kt) {
    if (kt == ktmax) {
      #pragma unroll
      for (int kt2 = 0; kt2 < 2; ++kt2)
        #pragma unroll
        for (int r = 0; r < 16; ++r) {
          int kg = kt * 64 + kt2 * 32 + (r & 3) + 8 * (r >> 2) + 4 * hi;
          if (kg > qmy) st[kt2][r] = -1e30f;
        }
    }
    float m0[8];
    #pragma unroll
    for (int i = 0; i < 8; ++i)
      m0[i] = max3f(st[0][i], st[0][i + 8], fmaxf(st[1][i], st[1][i + 8]));
    float mt = max3f(max3f(m0[0], m0[1], m0[2]), max3f(m0[3], m0[4], m0[5]),
                     fmaxf(m0[6], m0[7]));
    if (__any((mt - m_) * cexp > 8.0f)) {   // defer-max (T13)
      float mg = fmaxf(mt, __shfl_xor(mt, 32, 64));   // row max (pair-synced)
      float mn = fmaxf(m_, mg);
      float al = __builtin_amdgcn_exp2f((m_ - mn) * cexp);
      m_ = mn;
      la[0] *= al;                          // only element 0 of la is ever read
      #pragma unroll
      for (int dt = 0; dt < 2; ++dt)
        #pragma unroll
        for (int r = 0; r < 16; ++r) oa[dt][r] *= al;
    }
    const float mc = m_ * cexp;
    #pragma unroll
    for (int kt2 = 0; kt2 < 2; ++kt2)
      #pragma unroll
      for (int r = 0; r < 16; ++r)
        st[kt2][r] = __builtin_amdgcn_exp2f(fmaf(st[kt2][r], cexp, -mc));
    bf16x8 pfr[4];
    #pragma unroll
    for (int ks = 0; ks < 4; ++ks) {
      int tt = ks >> 1, gX = 2 * (ks & 1), gY = gX + 1;
      unsigned int x1 = cvtpk(st[tt][4 * gX + 0], st[tt][4 * gX + 1]);
      unsigned int y1 = cvtpk(st[tt][4 * gY + 0], st[tt][4 * gY + 1]);
      plswap(x1, y1);
      unsigned int x2 = cvtpk(st[tt][4 * gX + 2], st[tt][4 * gX + 3]);
      unsigned int y2 = cvtpk(st[tt][4 * gY + 2], st[tt][4 * gY + 3]);
      plswap(x2, y2);
      union { unsigned int u[4]; bf16x8 b; } cc;
      cc.u[0] = x1; cc.u[1] = x2; cc.u[2] = y1; cc.u[3] = y2;
      pfr[ks] = cc.b;
    }
    const int vb = kt % 3;
    __builtin_amdgcn_s_setprio(1);
    #pragma unroll
    for (int ks = 0; ks < 4; ++ks) {
      // l-row-sum on the matrix pipe: la[0] += sum_k P[k][q] (full row)
      la = __builtin_amdgcn_mfma_f32_32x32x16_bf16(onesf, pfr[ks], la, 0, 0, 0);
      #pragma unroll
      for (int dt = 0; dt < 2; ++dt) {
        int vrow = dt * 32 + q31;
        bf16x8 vf = *(const bf16x8*)&Vl[vb][vrow * 64 + (((2 * ks + hi) ^ (vrow & 7)) * 8)];
        oa[dt] = __builtin_amdgcn_mfma_f32_32x32x16_bf16(vf, pfr[ks], oa[dt], 0, 0, 0);
      }
    }
    __builtin_amdgcn_s_setprio(0);
  };

  f32x16 stA[2], stB[2];

  // prologue: tiles 0 and 1 in flight; compute S(0) once tile 0 lands
  STAGE(0);
  STAGE(1);
  asm volatile("s_waitcnt vmcnt(4)" ::: "memory");   // stage(0) landed (Q loads older)
  __builtin_amdgcn_s_barrier();
  __builtin_amdgcn_sched_barrier(0);
  QK(stA, 0);

  // one pipeline step: QK(kt+1) first, then SMPV(kt)
  auto STEP = [&](f32x16 (&cur)[2], f32x16 (&nxt)[2], int kt) {
    asm volatile("s_waitcnt vmcnt(0)" ::: "memory"); // stage(kt+1) landed
    __builtin_amdgcn_s_barrier();                    // all waves done with step kt-1
    __builtin_amdgcn_sched_barrier(0);
    if (kt + 1 < NT && kt + 1 <= ktmax) QK(nxt, (kt + 1) % 3);
    if (kt + 2 < NT) STAGE(kt + 2);
    if (kt <= ktmax) SMPV(cur, kt);
  };

  int kt = 0;
  while (kt < NT) {
    STEP(stA, stB, kt); ++kt;
    if (kt < NT) { STEP(stB, stA, kt); ++kt; }
  }

  // ---- epilogue: la[0] is the full (rescaled) row sum ----
  float inv = 1.0f / la[0];
  #pragma unroll
  for (int dt = 0; dt < 2; ++dt)
    #pragma unroll
    for (int g = 0; g < 4; ++g) {
      ushort4 o4;
      o4.x = f2bf(oa[dt][4 * g + 0] * inv);
      o4.y = f2bf(oa[dt][4 * g + 1] * inv);
      o4.z = f2bf(oa[dt][4 * g + 2] * inv);
      o4.w = f2bf(oa[dt][4 * g + 3] * inv);
      *(ushort4*)&O[qgrow * 1024 + h * 64 + dt * 32 + 8 * g + 4 * hi] = o4;
    }
}

// ---------------- launch ----------------
extern "C" void kernel_launch(void* const* d_in, const int* in_sizes, int n_in,
                              void* d_out, int out_size, void* d_ws, size_t ws_size,
                              hipStream_t stream) {
  const float* x  = (const float*)d_in[0];
  const float* Wq = (const float*)d_in[1];
  const float* Wk = (const float*)d_in[2];
  const float* Wv = (const float*)d_in[3];
  const float* Wo = (const float*)d_in[4];
  char* ws = (char*)d_ws;
  unsigned short* xb   = (unsigned short*)(ws);                    // 8 MiB (x bf16; later reused as Vt)
  unsigned short* Wb   = (unsigned short*)(ws + (8u << 20));       // 6 MiB
  unsigned short* Wob  = (unsigned short*)(ws + (14u << 20));      // 2 MiB
  unsigned short* QKVb = (unsigned short*)(ws + (16u << 20));      // 24 MiB
  unsigned short* Ob   = (unsigned short*)(ws + (40u << 20));      // 8 MiB
  unsigned short* Vtg  = xb;                                       // reuse: x dead after QKV GEMM

  cvt_k<<<4096, 256, 0, stream>>>(x, xb, 4096 * 1024 / 4);
  cvt_k<<<1024, 256, 0, stream>>>(Wq, Wb, 1024 * 1024 / 4);
  cvt_k<<<1024, 256, 0, stream>>>(Wk, Wb + 1024 * 1024, 1024 * 1024 / 4);
  cvt_k<<<1024, 256, 0, stream>>>(Wv, Wb + 2 * 1024 * 1024, 1024 * 1024 / 4);
  cvt_k<<<1024, 256, 0, stream>>>(Wo, Wob, 1024 * 1024 / 4);

  gemm_bt<0><<<dim3(32, 24), 256, 0, stream>>>(xb, Wb, QKVb, 3072, 1024);
  rope_k<<<4096, 256, 0, stream>>>(QKVb);
  vtr_k<<<dim3(32, 32), 256, 0, stream>>>(QKVb, Vtg);
  attn_k<<<dim3(32, 16), 256, 0, stream>>>(QKVb, Vtg, Ob);
  gemm_bt<1><<<dim3(32, 8), 256, 0, stream>>>(Ob, Wob, d_out, 1024, 1024);
}